// Round 2
// 528.137 us; speedup vs baseline: 1.0861x; 1.0861x over previous
//
#include <hip/hip_runtime.h>
#include <stdint.h>

// ---------------------------------------------------------------------------
// FourierLayer: 5x [conv2x2s2 + BN(eval) + ReLU] -> fuse proj -> rFFT(32) ->
// gating (top-3 softmax) on MI355X.
//
// Round-N changes vs 571.7us baseline:
//  * layers 1-3: gemm64_kernel, 64x256 tile (grids 256/64/16 -> full-GPU
//    parallelism at layer1), double-buffered LDS (80 KB): issue kt+1 stage
//    into buf^1 BEFORE computing kt, then one __syncthreads() per K-step
//    (its vmcnt drain is semantically required there anyway -> prefetch
//    latency hides under compute). MFMA k-order identical to the old
//    kernel -> bitwise-identical intermediates.
//  * layer4 + fuse_proj fused into tail_kernel (2 blocks): layer4's 128x256
//    output tile == fuse's A-tile for the same rows; kept in LDS as bf16 with
//    the same XOR-8 16B-unit swizzle, killing the inter4 round-trip + launch.
//  * prep / layer0 / fft_gate / finalize unchanged (layer0 is HBM-bound at
//    its 41us floor reading the 256MB fp32 input once).
// ---------------------------------------------------------------------------

typedef __attribute__((ext_vector_type(8))) short bf16x8;
typedef __attribute__((ext_vector_type(4))) float f32x4;

#define DEV __device__ __forceinline__
#define GLOBAL_AS __attribute__((address_space(1)))
#define LDS_AS __attribute__((address_space(3)))

DEV unsigned short f2bf(float f) {
  union { float f; uint32_t u; } v; v.f = f;
  uint32_t u = v.u;
  return (unsigned short)((u + 0x7fffu + ((u >> 16) & 1u)) >> 16);
}

DEV void async16(const void* g, void* l) {
  __builtin_amdgcn_global_load_lds((GLOBAL_AS void*)g, (LDS_AS void*)l, 16, 0, 0);
}

// --------------------------- weight prep ----------------------------------
// idx < 262144: layer0 B image [kt(16)][u(8)][c(256)][kv(8)], k=q*16+ci_l,
//               u=k>>3 (q=u>>1, ci_l=(u&1)*8+kv), ci=kt*16+ci_l.
// else l=1..4:  Bt[l][co][k=q*256+ci] (patch-Z A order). Then Bt_fuse, bias.
__global__ void prep_kernel(const float* __restrict__ conv_w,
                            const float* __restrict__ conv_b,
                            const float* __restrict__ gamma,
                            const float* __restrict__ beta,
                            const float* __restrict__ mean,
                            const float* __restrict__ var,
                            const float* __restrict__ fuse_w,
                            unsigned short* __restrict__ Bt_all,
                            unsigned short* __restrict__ Bt_fuse,
                            float* __restrict__ bias_all) {
  int idx = blockIdx.x * 256 + threadIdx.x;
  const int NB = 5 * 256 * 1024;
  if (idx < 262144) {
    int kv = idx & 7;
    int c = (idx >> 3) & 255;
    int u = (idx >> 11) & 7;
    int kt = idx >> 14;
    int q = u >> 1;
    int ci = kt * 16 + (u & 1) * 8 + kv;
    float scale = gamma[c] * rsqrtf(var[c] + 1e-5f);
    Bt_all[idx] = f2bf(conv_w[(((size_t)c * 256 + ci) << 2) + q] * scale);
  } else if (idx < NB) {
    int l = idx >> 18;  // 1..4
    int rem = idx & 262143;
    int co = rem >> 10;
    int k = rem & 1023;
    int q = k >> 8;
    int ci = k & 255;
    int lc = l * 256 + co;
    float scale = gamma[lc] * rsqrtf(var[lc] + 1e-5f);
    Bt_all[idx] = f2bf(conv_w[(((size_t)lc * 256 + ci) << 2) + q] * scale);
  } else if (idx < NB + 65536) {
    int i = idx - NB;
    Bt_fuse[i] = f2bf(fuse_w[i]);
  } else if (idx < NB + 65536 + 1280) {
    int j = idx - (NB + 65536);
    float scale = gamma[j] * rsqrtf(var[j] + 1e-5f);
    bias_all[j] = (conv_b[j] - mean[j]) * scale + beta[j];
  }
}

// --------------------------- layer 0 (fused im2col GEMM) --------------------
// Block = (n = blk>>1, yh = blk&1): rows r = (Yl>>1)*16 + xp, Yl in [0,16),
// Y_img = yh*16 + Yl. K-tile kt: ci in [kt*16, kt*16+16), all 4 q.
// As: [u(8)][rsw(128)][kv(8)] bf16, rsw = (r&0x78)|((r^(r>>3))&7).
// Bs: [u(8)][c(256)][kv(8)] bf16, staged contiguously via async16.
__global__ __launch_bounds__(256, 2) void layer0_kernel(
    const float* __restrict__ X, const unsigned short* __restrict__ Bt0,
    const float* __restrict__ bias, unsigned short* __restrict__ Out) {
  __shared__ __align__(16) unsigned short As[8192];
  __shared__ __align__(16) unsigned short Bs[16384];
  const int t = threadIdx.x;
  const int lane = t & 63, wave = t >> 6;
  const int n = blockIdx.x >> 1, yh = blockIdx.x & 1;
  const int m16 = lane & 15, quad = lane >> 4;
  const int rw = wave >> 1, cw = wave & 1;
  const int xq = lane & 7, ci_lo = lane >> 3;  // ci varies within wave
  const float* xn = X + (size_t)n * 262144 + (size_t)(yh * 16) * 32;

  const f32x4 zero = {0.f, 0.f, 0.f, 0.f};
  f32x4 acc[4][8];
#pragma unroll
  for (int i = 0; i < 4; ++i)
#pragma unroll
    for (int j = 0; j < 8; ++j) acc[i][j] = zero;

  for (int kt = 0; kt < 16; ++kt) {
    // B stage: 32 KB contiguous
#pragma unroll
    for (int i = 0; i < 8; ++i)
      async16(Bt0 + (size_t)kt * 16384 + (i * 256 + t) * 8,
              &Bs[(i * 256 + t) * 8]);
    // A stage: 8 float4 loads -> 32 bf16 scattered writes
#pragma unroll
    for (int j = 0; j < 8; ++j) {
      int Yl = wave * 4 + (j & 3);
      int ci_l = (j >> 2) * 8 + ci_lo;
      int ci = kt * 16 + ci_l;
      const float4 f = *(const float4*)(xn + (size_t)ci * 1024 + Yl * 32 + xq * 4);
      int qY = (Yl & 1) * 2;
      int rb = (Yl >> 1) * 16 + xq * 2;
      int cihi = ci_l >> 3, kv = ci_l & 7;
      int u0 = qY * 2 + cihi;
      int r0s = (rb & 0x78) | ((rb ^ (rb >> 3)) & 7);
      int r1 = rb + 1;
      int r1s = (r1 & 0x78) | ((r1 ^ (r1 >> 3)) & 7);
      As[u0 * 1024 + r0s * 8 + kv] = f2bf(f.x);
      As[(u0 + 2) * 1024 + r0s * 8 + kv] = f2bf(f.y);
      As[u0 * 1024 + r1s * 8 + kv] = f2bf(f.z);
      As[(u0 + 2) * 1024 + r1s * 8 + kv] = f2bf(f.w);
    }
    __syncthreads();  // drains async16 (vmcnt) + ds writes
#pragma unroll
    for (int ks = 0; ks < 2; ++ks) {
      bf16x8 af[4], bfr[8];
      int ul = ks * 4 + quad;
#pragma unroll
      for (int f = 0; f < 4; ++f) {
        int r = rw * 64 + f * 16 + m16;
        int rs = (r & 0x78) | ((r ^ (r >> 3)) & 7);
        af[f] = *(const bf16x8*)&As[ul * 1024 + rs * 8];
      }
#pragma unroll
      for (int f = 0; f < 8; ++f) {
        int c = cw * 128 + f * 16 + m16;
        bfr[f] = *(const bf16x8*)&Bs[(ul * 256 + c) * 8];
      }
#pragma unroll
      for (int fi = 0; fi < 4; ++fi)
#pragma unroll
        for (int fj = 0; fj < 8; ++fj)
          acc[fi][fj] = __builtin_amdgcn_mfma_f32_16x16x32_bf16(
              af[fi], bfr[fj], acc[fi][fj], 0, 0, 0);
    }
    __syncthreads();  // LDS free for next tile's writes
  }

  float biasv[8];
#pragma unroll
  for (int fj = 0; fj < 8; ++fj) biasv[fj] = bias[cw * 128 + fj * 16 + m16];

#pragma unroll
  for (int fi = 0; fi < 4; ++fi) {
#pragma unroll
    for (int fj = 0; fj < 8; ++fj) {
      int col = cw * 128 + fj * 16 + m16;
      f32x4 v = acc[fi][fj];
#pragma unroll
      for (int i = 0; i < 4; ++i) {
        int rt = rw * 64 + fi * 16 + quad * 4 + i;
        int yo = yh * 8 + (rt >> 4);  // output pixel (16x16 grid)
        int xo = rt & 15;
        float val = fmaxf(v[i] + biasv[fj], 0.f);
        size_t addr = ((size_t)n << 16) + ((size_t)(yo >> 1) << 13) +
                      ((size_t)(xo >> 1) << 10) +
                      ((((yo & 1) << 1) | (xo & 1)) << 8) + col;
        Out[addr] = f2bf(val);
      }
    }
  }
}

// --------------------------- 64x256 dbuf GEMM (layers 1-3) ------------------
// C[M x 256] = A[M x K] * Bt[256 x K]^T + bias, ReLU, bf16 out in patch-Z.
// Tile 64 x 256, BK=64, 4 waves each own a 64-col quarter over all 64 rows
// (acc[4][4]). Double-buffered LDS (80 KB): issue stage of kt+1 into buf^1,
// compute kt from buf, then one __syncthreads() (prefetch latency hides
// under compute; its vmcnt drain is required there anyway since the next
// iteration reads buf^1 immediately). MFMA k-order identical to the old
// 128x256 kernel -> bitwise-identical outputs.
__global__ __launch_bounds__(256, 2) void gemm64_kernel(
    const unsigned short* __restrict__ A, const unsigned short* __restrict__ Bt,
    const float* __restrict__ bias, unsigned short* __restrict__ Out, int K,
    int hw_shift, int wsh) {
  __shared__ __align__(16) unsigned short As[2][64 * 64];    // 16 KB
  __shared__ __align__(16) unsigned short Bs[2][256 * 64];   // 64 KB
  const int t = threadIdx.x;
  const int lane = t & 63, wave = t >> 6;
  const int R0 = blockIdx.x * 64;
  const int m16 = lane & 15, quad = lane >> 4;

  const unsigned short* ga[2];
  const unsigned short* gb[8];
#pragma unroll
  for (int p = 0; p < 2; ++p) {
    int g = p * 256 + t;
    int r = g >> 3, u = g & 7;
    ga[p] = A + (size_t)(R0 + r) * K + ((u ^ (r & 7)) << 3);
  }
#pragma unroll
  for (int p = 0; p < 8; ++p) {
    int g = p * 256 + t;
    int r = g >> 3, u = g & 7;
    gb[p] = Bt + (size_t)r * K + ((u ^ (r & 7)) << 3);
  }

  const f32x4 zero = {0.f, 0.f, 0.f, 0.f};
  f32x4 acc[4][4];
#pragma unroll
  for (int i = 0; i < 4; ++i)
#pragma unroll
    for (int j = 0; j < 4; ++j) acc[i][j] = zero;

  const int kIters = K >> 6;
  // prologue: stage kt=0 -> buf0
#pragma unroll
  for (int p = 0; p < 2; ++p) async16(ga[p], &As[0][(p * 256 + t) * 8]);
#pragma unroll
  for (int p = 0; p < 8; ++p) async16(gb[p], &Bs[0][(p * 256 + t) * 8]);
  __syncthreads();

  for (int kt = 0; kt < kIters; ++kt) {
    const int cur = kt & 1;
    if (kt + 1 < kIters) {  // prefetch next K-tile into the other buffer
#pragma unroll
      for (int p = 0; p < 2; ++p)
        async16(ga[p] + (kt + 1) * 64, &As[cur ^ 1][(p * 256 + t) * 8]);
#pragma unroll
      for (int p = 0; p < 8; ++p)
        async16(gb[p] + (kt + 1) * 64, &Bs[cur ^ 1][(p * 256 + t) * 8]);
    }
#pragma unroll
    for (int ks = 0; ks < 2; ++ks) {
      bf16x8 af[4], bfr[4];
      int ul = (ks << 2) + quad;
#pragma unroll
      for (int f = 0; f < 4; ++f) {
        int ra = f * 16 + m16;
        af[f] = *(const bf16x8*)&As[cur][ra * 64 + ((ul ^ (ra & 7)) << 3)];
      }
#pragma unroll
      for (int f = 0; f < 4; ++f) {
        int rb = wave * 64 + f * 16 + m16;
        bfr[f] = *(const bf16x8*)&Bs[cur][rb * 64 + ((ul ^ (rb & 7)) << 3)];
      }
#pragma unroll
      for (int fi = 0; fi < 4; ++fi)
#pragma unroll
        for (int fj = 0; fj < 4; ++fj)
          acc[fi][fj] = __builtin_amdgcn_mfma_f32_16x16x32_bf16(
              af[fi], bfr[fj], acc[fi][fj], 0, 0, 0);
    }
    __syncthreads();  // drains prefetch (needed next iter) + guards buf reuse
  }

  float biasv[4];
#pragma unroll
  for (int fj = 0; fj < 4; ++fj) biasv[fj] = bias[wave * 64 + fj * 16 + m16];

#pragma unroll
  for (int fi = 0; fi < 4; ++fi) {
#pragma unroll
    for (int fj = 0; fj < 4; ++fj) {
      int col = wave * 64 + fj * 16 + m16;
      f32x4 v = acc[fi][fj];
#pragma unroll
      for (int i = 0; i < 4; ++i) {
        int R = R0 + fi * 16 + quad * 4 + i;
        float val = fmaxf(v[i] + biasv[fj], 0.f);
        int n = R >> hw_shift;
        int rem = R & ((1 << hw_shift) - 1);
        int y = rem >> wsh;
        int x = rem & ((1 << wsh) - 1);
        int q2 = ((y & 1) << 1) | (x & 1);
        size_t addr = ((size_t)n << (hw_shift + 8)) +
                      ((size_t)(y >> 1) << (wsh + 9)) +
                      ((size_t)(x >> 1) << 10) + (q2 << 8) + col;
        Out[addr] = f2bf(val);
      }
    }
  }
}

// --------------------------- tail: layer4 + fuse proj -----------------------
// Grid 2 x 256. Block covers rows R0..R0+127 of both layer4 and fuse (same
// rows!), so layer4's output tile is kept in LDS (bf16, XOR-8 16B-unit
// swizzle) and serves as fuse's A operand. Saves inter4 round-trip + launch.
__global__ __launch_bounds__(256, 1) void tail_kernel(
    const unsigned short* __restrict__ A,    // inter3 [256 x 1024]
    const unsigned short* __restrict__ Bt4,  // layer4 weights [256 x 1024]
    const float* __restrict__ bias4,
    const unsigned short* __restrict__ Btf,  // fuse weights [256 x 256]
    const float* __restrict__ fbias,
    float* __restrict__ hbuf) {
  __shared__ __align__(16) unsigned short As[128 * 64];   // 16 KB staging
  __shared__ __align__(16) unsigned short Bs[256 * 64];   // 32 KB staging
  __shared__ __align__(16) unsigned short C4s[128 * 256]; // 64 KB layer4 out
  const int t = threadIdx.x;
  const int lane = t & 63, wave = t >> 6;
  const int R0 = blockIdx.x * 128;
  const int rw = wave >> 1, cw = wave & 1;
  const int m16 = lane & 15, quad = lane >> 4;

  // ---- layer4 GEMM: 128x256 tile, K=1024, single-buffered (L2-resident) ---
  const unsigned short* ga[4];
  const unsigned short* gb[8];
#pragma unroll
  for (int p = 0; p < 4; ++p) {
    int g = p * 256 + t;
    int r = g >> 3, u = g & 7;
    ga[p] = A + (size_t)(R0 + r) * 1024 + ((u ^ (r & 7)) << 3);
  }
#pragma unroll
  for (int p = 0; p < 8; ++p) {
    int g = p * 256 + t;
    int r = g >> 3, u = g & 7;
    gb[p] = Bt4 + (size_t)r * 1024 + ((u ^ (r & 7)) << 3);
  }

  const f32x4 zero = {0.f, 0.f, 0.f, 0.f};
  f32x4 acc[4][8];
#pragma unroll
  for (int i = 0; i < 4; ++i)
#pragma unroll
    for (int j = 0; j < 8; ++j) acc[i][j] = zero;

  for (int kt = 0; kt < 16; ++kt) {
#pragma unroll
    for (int p = 0; p < 4; ++p) {
      async16(ga[p], &As[(p * 256 + t) * 8]);
      ga[p] += 64;
    }
#pragma unroll
    for (int p = 0; p < 8; ++p) {
      async16(gb[p], &Bs[(p * 256 + t) * 8]);
      gb[p] += 64;
    }
    __syncthreads();
#pragma unroll
    for (int ks = 0; ks < 2; ++ks) {
      bf16x8 af[4], bfr[8];
      int ul = (ks << 2) + quad;
#pragma unroll
      for (int f = 0; f < 4; ++f) {
        int ra = rw * 64 + f * 16 + m16;
        af[f] = *(const bf16x8*)&As[ra * 64 + ((ul ^ (ra & 7)) << 3)];
      }
#pragma unroll
      for (int f = 0; f < 8; ++f) {
        int rb = cw * 128 + f * 16 + m16;
        bfr[f] = *(const bf16x8*)&Bs[rb * 64 + ((ul ^ (rb & 7)) << 3)];
      }
#pragma unroll
      for (int fi = 0; fi < 4; ++fi)
#pragma unroll
        for (int fj = 0; fj < 8; ++fj)
          acc[fi][fj] = __builtin_amdgcn_mfma_f32_16x16x32_bf16(
              af[fi], bfr[fj], acc[fi][fj], 0, 0, 0);
    }
    __syncthreads();
  }

  // bias + ReLU -> C4s (bf16), element (rt,k) at rt*256 + ((k>>3)^(rt&7))*8
  // + (k&7)  (XOR only touches the low 3 bits of the 16B-unit index).
  {
    float b4[8];
#pragma unroll
    for (int fj = 0; fj < 8; ++fj) b4[fj] = bias4[cw * 128 + fj * 16 + m16];
#pragma unroll
    for (int fi = 0; fi < 4; ++fi) {
#pragma unroll
      for (int fj = 0; fj < 8; ++fj) {
        int col = cw * 128 + fj * 16 + m16;
        int uu = col >> 3, klo = col & 7;
        f32x4 v = acc[fi][fj];
#pragma unroll
        for (int i = 0; i < 4; ++i) {
          int rt = rw * 64 + fi * 16 + quad * 4 + i;
          float val = fmaxf(v[i] + b4[fj], 0.f);
          C4s[rt * 256 + ((uu ^ (rt & 7)) << 3) + klo] = f2bf(val);
        }
      }
    }
  }
  __syncthreads();

  // ---- fuse GEMM: A = C4s (LDS), B = Btf staged, K = 256 (4 K-tiles) ------
  const unsigned short* gf[8];
#pragma unroll
  for (int p = 0; p < 8; ++p) {
    int g = p * 256 + t;
    int r = g >> 3, u = g & 7;
    gf[p] = Btf + (size_t)r * 256 + ((u ^ (r & 7)) << 3);
  }
  f32x4 acc2[4][8];
#pragma unroll
  for (int i = 0; i < 4; ++i)
#pragma unroll
    for (int j = 0; j < 8; ++j) acc2[i][j] = zero;

  for (int kt2 = 0; kt2 < 4; ++kt2) {
#pragma unroll
    for (int p = 0; p < 8; ++p) {
      async16(gf[p], &Bs[(p * 256 + t) * 8]);
      gf[p] += 64;
    }
    __syncthreads();
#pragma unroll
    for (int ks = 0; ks < 2; ++ks) {
      bf16x8 af[4], bfr[8];
      int ul = (ks << 2) + quad;
#pragma unroll
      for (int f = 0; f < 4; ++f) {
        int ra = rw * 64 + f * 16 + m16;
        af[f] = *(const bf16x8*)&C4s[ra * 256 +
                                     ((kt2 * 8 + (ul ^ (ra & 7))) << 3)];
      }
#pragma unroll
      for (int f = 0; f < 8; ++f) {
        int rb = cw * 128 + f * 16 + m16;
        bfr[f] = *(const bf16x8*)&Bs[rb * 64 + ((ul ^ (rb & 7)) << 3)];
      }
#pragma unroll
      for (int fi = 0; fi < 4; ++fi)
#pragma unroll
        for (int fj = 0; fj < 8; ++fj)
          acc2[fi][fj] = __builtin_amdgcn_mfma_f32_16x16x32_bf16(
              af[fi], bfr[fj], acc2[fi][fj], 0, 0, 0);
    }
    __syncthreads();
  }

  // f32 output, no ReLU, dense [R][col]
  {
    float fb[8];
#pragma unroll
    for (int fj = 0; fj < 8; ++fj) fb[fj] = fbias[cw * 128 + fj * 16 + m16];
#pragma unroll
    for (int fi = 0; fi < 4; ++fi) {
#pragma unroll
      for (int fj = 0; fj < 8; ++fj) {
        int col = cw * 128 + fj * 16 + m16;
        f32x4 v = acc2[fi][fj];
#pragma unroll
        for (int i = 0; i < 4; ++i) {
          int R = R0 + rw * 64 + fi * 16 + quad * 4 + i;
          hbuf[((size_t)R << 8) + col] = v[i] + fb[fj];
        }
      }
    }
  }
}

// --------------------------- FFT + gate logits ------------------------------
__global__ void fft_gate_kernel(const float* __restrict__ hbuf,
                                const float* __restrict__ w_gate,
                                float* __restrict__ weights) {
  __shared__ float cs[32], sn[32];
  __shared__ float wg[144];
  __shared__ float red[4][9];
  const int b = blockIdx.x, t = threadIdx.x;
  if (t < 32) {
    float ang = 6.283185307179586f * (float)t / 32.0f;
    cs[t] = cosf(ang);
    sn[t] = sinf(ang);
  }
  if (t < 144) wg[t] = w_gate[t];
  __syncthreads();

  float hl[32];
#pragma unroll
  for (int tt = 0; tt < 32; ++tt) hl[tt] = hbuf[(size_t)(b * 32 + tt) * 256 + t];

  float lg[9];
#pragma unroll
  for (int s = 0; s < 9; ++s) lg[s] = 0.f;

#pragma unroll
  for (int f = 1; f <= 16; ++f) {
    float re = 0.f, im = 0.f;
#pragma unroll
    for (int tt = 0; tt < 32; ++tt) {
      int idx = (f * tt) & 31;
      re += hl[tt] * cs[idx];
      im += hl[tt] * sn[idx];
    }
    float amp = sqrtf(re * re + im * im) * 0.17677669529663687f;  // 1/sqrt(32)
#pragma unroll
    for (int s = 0; s < 9; ++s) lg[s] += amp * wg[(f - 1) * 9 + s];
  }

  const int lane = t & 63, wave = t >> 6;
#pragma unroll
  for (int s = 0; s < 9; ++s) {
    float v = lg[s];
    v += __shfl_down(v, 32, 64);
    v += __shfl_down(v, 16, 64);
    v += __shfl_down(v, 8, 64);
    v += __shfl_down(v, 4, 64);
    v += __shfl_down(v, 2, 64);
    v += __shfl_down(v, 1, 64);
    if (lane == 0) red[wave][s] = v;
  }
  __syncthreads();
  if (t < 9) {
    float total = red[0][t] + red[1][t] + red[2][t] + red[3][t];
    weights[b * 9 + t] = total * (1.0f / 256.0f);
  }
}

// --------------------------- finalize: top-k gates + load -------------------
__global__ void finalize_kernel(const float* __restrict__ weights,
                                float* __restrict__ out) {
  const int t = threadIdx.x;
  if (t < 8) {
    float w[9];
    int idx[9];
#pragma unroll
    for (int s = 0; s < 9; ++s) {
      w[s] = weights[t * 9 + s];
      idx[s] = s;
    }
    for (int a = 0; a < 4; ++a) {
      int best = a;
      for (int c = a + 1; c < 9; ++c)
        if (w[idx[c]] > w[idx[best]]) best = c;
      int tmp = idx[a];
      idx[a] = idx[best];
      idx[best] = tmp;
    }
    float m = w[idx[0]];
    float e0 = expf(w[idx[0]] - m);
    float e1 = expf(w[idx[1]] - m);
    float e2 = expf(w[idx[2]] - m);
    float inv = 1.0f / (e0 + e1 + e2);
    float g[9];
#pragma unroll
    for (int s = 0; s < 9; ++s) g[s] = 0.f;
    g[idx[0]] = e0 * inv;
    g[idx[1]] = e1 * inv;
    g[idx[2]] = e2 * inv;
#pragma unroll
    for (int s = 0; s < 9; ++s) out[t * 9 + s] = g[s];
  }
  __syncthreads();
  if (t < 9) {
    int cnt = 0;
#pragma unroll
    for (int b = 0; b < 8; ++b) cnt += (out[b * 9 + t] > 0.f) ? 1 : 0;
    out[72 + t] = (float)cnt;
  }
}

// --------------------------- launch ----------------------------------------
extern "C" void kernel_launch(void* const* d_in, const int* in_sizes, int n_in,
                              void* d_out, int out_size, void* d_ws,
                              size_t ws_size, hipStream_t stream) {
  (void)in_sizes; (void)n_in; (void)out_size; (void)ws_size;
  const float* x      = (const float*)d_in[0];
  const float* conv_w = (const float*)d_in[1];
  const float* conv_b = (const float*)d_in[2];
  const float* gamma  = (const float*)d_in[3];
  const float* beta   = (const float*)d_in[4];
  const float* mean   = (const float*)d_in[5];
  const float* var    = (const float*)d_in[6];
  const float* fuse_w = (const float*)d_in[7];
  const float* fuse_b = (const float*)d_in[8];
  const float* w_gate = (const float*)d_in[9];

  char* ws = (char*)d_ws;
  size_t off = 0;
  auto alloc = [&](size_t bytes) {
    void* p = ws + off;
    off = (off + bytes + 255) & ~(size_t)255;
    return p;
  };
  unsigned short* Bt_all  = (unsigned short*)alloc((size_t)5 * 262144 * 2);
  unsigned short* Bt_fuse = (unsigned short*)alloc((size_t)65536 * 2);
  float* bias_all         = (float*)alloc(1280 * 4);
  unsigned short* inter0  = (unsigned short*)alloc((size_t)65536 * 256 * 2);
  unsigned short* inter1  = (unsigned short*)alloc((size_t)16384 * 256 * 2);
  unsigned short* inter2  = (unsigned short*)alloc((size_t)4096 * 256 * 2);
  unsigned short* inter3  = (unsigned short*)alloc((size_t)1024 * 256 * 2);
  float* hbuf             = (float*)alloc((size_t)256 * 256 * 4);
  float* wts              = (float*)alloc(72 * 4);

  prep_kernel<<<5381, 256, 0, stream>>>(conv_w, conv_b, gamma, beta, mean, var,
                                        fuse_w, Bt_all, Bt_fuse, bias_all);
  layer0_kernel<<<512, 256, 0, stream>>>(x, Bt_all, bias_all, inter0);
  gemm64_kernel<<<256, 256, 0, stream>>>(
      inter0, Bt_all + 262144, bias_all + 256, inter1, 1024, 6, 3);
  gemm64_kernel<<<64, 256, 0, stream>>>(
      inter1, Bt_all + 2 * 262144, bias_all + 512, inter2, 1024, 4, 2);
  gemm64_kernel<<<16, 256, 0, stream>>>(
      inter2, Bt_all + 3 * 262144, bias_all + 768, inter3, 1024, 2, 1);
  tail_kernel<<<2, 256, 0, stream>>>(
      inter3, Bt_all + 4 * 262144, bias_all + 1024, Bt_fuse, fuse_b, hbuf);
  fft_gate_kernel<<<8, 256, 0, stream>>>(hbuf, w_gate, wts);
  finalize_kernel<<<1, 64, 0, stream>>>(wts, (float*)d_out);
}

// Round 3
// 525.219 us; speedup vs baseline: 1.0922x; 1.0056x over previous
//
#include <hip/hip_runtime.h>
#include <stdint.h>

// ---------------------------------------------------------------------------
// FourierLayer: 5x [conv2x2s2 + BN(eval) + ReLU] -> fuse proj -> rFFT(32) ->
// gating (top-3 softmax) on MI355X.
//
// Pipeline (5 dispatches):
//   prep -> layer0 (fused im2col GEMM, HBM-bound ~41us floor)
//        -> gemm64 (layer1, 256 blocks, dbuf)
//        -> megatail (layers 2+3+4+fuse in ONE kernel, grid 32)
//        -> fft_gate (+fused finalize via last-block elect)
//
// megatail exploits patch-Z nesting: block b owns images [8b,8b+8) ->
// layer2 rows [128b,+128), layer3 [32b,+32), layer4 [8b,+8), fuse [8b,+8);
// all deps in-block. Intermediates live in LDS (C2s 64KB, C3s aliases As
// staging, C4s 4KB), XOR-8 swizzled so GEMM A-reads are ds_read_b128
// conflict-free. MFMA k-order identical everywhere -> bitwise-identical.
// ---------------------------------------------------------------------------

typedef __attribute__((ext_vector_type(8))) short bf16x8;
typedef __attribute__((ext_vector_type(4))) float f32x4;

#define DEV __device__ __forceinline__
#define GLOBAL_AS __attribute__((address_space(1)))
#define LDS_AS __attribute__((address_space(3)))

DEV unsigned short f2bf(float f) {
  union { float f; uint32_t u; } v; v.f = f;
  uint32_t u = v.u;
  return (unsigned short)((u + 0x7fffu + ((u >> 16) & 1u)) >> 16);
}

DEV void async16(const void* g, void* l) {
  __builtin_amdgcn_global_load_lds((GLOBAL_AS void*)g, (LDS_AS void*)l, 16, 0, 0);
}

// --------------------------- weight prep ----------------------------------
// idx < 262144: layer0 B image [kt(16)][u(8)][c(256)][kv(8)], k=q*16+ci_l,
//               u=k>>3 (q=u>>1, ci_l=(u&1)*8+kv), ci=kt*16+ci_l.
// else l=1..4:  Bt[l][co][k=q*256+ci] (patch-Z A order). Then Bt_fuse, bias,
// and the fft_gate election counter (zeroed each iteration).
__global__ void prep_kernel(const float* __restrict__ conv_w,
                            const float* __restrict__ conv_b,
                            const float* __restrict__ gamma,
                            const float* __restrict__ beta,
                            const float* __restrict__ mean,
                            const float* __restrict__ var,
                            const float* __restrict__ fuse_w,
                            unsigned short* __restrict__ Bt_all,
                            unsigned short* __restrict__ Bt_fuse,
                            float* __restrict__ bias_all,
                            int* __restrict__ counter) {
  int idx = blockIdx.x * 256 + threadIdx.x;
  const int NB = 5 * 256 * 1024;
  if (idx < 262144) {
    int kv = idx & 7;
    int c = (idx >> 3) & 255;
    int u = (idx >> 11) & 7;
    int kt = idx >> 14;
    int q = u >> 1;
    int ci = kt * 16 + (u & 1) * 8 + kv;
    float scale = gamma[c] * rsqrtf(var[c] + 1e-5f);
    Bt_all[idx] = f2bf(conv_w[(((size_t)c * 256 + ci) << 2) + q] * scale);
  } else if (idx < NB) {
    int l = idx >> 18;  // 1..4
    int rem = idx & 262143;
    int co = rem >> 10;
    int k = rem & 1023;
    int q = k >> 8;
    int ci = k & 255;
    int lc = l * 256 + co;
    float scale = gamma[lc] * rsqrtf(var[lc] + 1e-5f);
    Bt_all[idx] = f2bf(conv_w[(((size_t)lc * 256 + ci) << 2) + q] * scale);
  } else if (idx < NB + 65536) {
    int i = idx - NB;
    Bt_fuse[i] = f2bf(fuse_w[i]);
  } else if (idx < NB + 65536 + 1280) {
    int j = idx - (NB + 65536);
    float scale = gamma[j] * rsqrtf(var[j] + 1e-5f);
    bias_all[j] = (conv_b[j] - mean[j]) * scale + beta[j];
  } else if (idx == NB + 65536 + 1280) {
    *counter = 0;
  }
}

// --------------------------- layer 0 (fused im2col GEMM) --------------------
// Block = (n = blk>>1, yh = blk&1): rows r = (Yl>>1)*16 + xp, Yl in [0,16),
// Y_img = yh*16 + Yl. K-tile kt: ci in [kt*16, kt*16+16), all 4 q.
// As: [u(8)][rsw(128)][kv(8)] bf16, rsw = (r&0x78)|((r^(r>>3))&7).
// Bs: [u(8)][c(256)][kv(8)] bf16, staged contiguously via async16.
__global__ __launch_bounds__(256, 2) void layer0_kernel(
    const float* __restrict__ X, const unsigned short* __restrict__ Bt0,
    const float* __restrict__ bias, unsigned short* __restrict__ Out) {
  __shared__ __align__(16) unsigned short As[8192];
  __shared__ __align__(16) unsigned short Bs[16384];
  const int t = threadIdx.x;
  const int lane = t & 63, wave = t >> 6;
  const int n = blockIdx.x >> 1, yh = blockIdx.x & 1;
  const int m16 = lane & 15, quad = lane >> 4;
  const int rw = wave >> 1, cw = wave & 1;
  const int xq = lane & 7, ci_lo = lane >> 3;  // ci varies within wave
  const float* xn = X + (size_t)n * 262144 + (size_t)(yh * 16) * 32;

  const f32x4 zero = {0.f, 0.f, 0.f, 0.f};
  f32x4 acc[4][8];
#pragma unroll
  for (int i = 0; i < 4; ++i)
#pragma unroll
    for (int j = 0; j < 8; ++j) acc[i][j] = zero;

  for (int kt = 0; kt < 16; ++kt) {
    // B stage: 32 KB contiguous
#pragma unroll
    for (int i = 0; i < 8; ++i)
      async16(Bt0 + (size_t)kt * 16384 + (i * 256 + t) * 8,
              &Bs[(i * 256 + t) * 8]);
    // A stage: 8 float4 loads -> 32 bf16 scattered writes
#pragma unroll
    for (int j = 0; j < 8; ++j) {
      int Yl = wave * 4 + (j & 3);
      int ci_l = (j >> 2) * 8 + ci_lo;
      int ci = kt * 16 + ci_l;
      const float4 f = *(const float4*)(xn + (size_t)ci * 1024 + Yl * 32 + xq * 4);
      int qY = (Yl & 1) * 2;
      int rb = (Yl >> 1) * 16 + xq * 2;
      int cihi = ci_l >> 3, kv = ci_l & 7;
      int u0 = qY * 2 + cihi;
      int r0s = (rb & 0x78) | ((rb ^ (rb >> 3)) & 7);
      int r1 = rb + 1;
      int r1s = (r1 & 0x78) | ((r1 ^ (r1 >> 3)) & 7);
      As[u0 * 1024 + r0s * 8 + kv] = f2bf(f.x);
      As[(u0 + 2) * 1024 + r0s * 8 + kv] = f2bf(f.y);
      As[u0 * 1024 + r1s * 8 + kv] = f2bf(f.z);
      As[(u0 + 2) * 1024 + r1s * 8 + kv] = f2bf(f.w);
    }
    __syncthreads();  // drains async16 (vmcnt) + ds writes
#pragma unroll
    for (int ks = 0; ks < 2; ++ks) {
      bf16x8 af[4], bfr[8];
      int ul = ks * 4 + quad;
#pragma unroll
      for (int f = 0; f < 4; ++f) {
        int r = rw * 64 + f * 16 + m16;
        int rs = (r & 0x78) | ((r ^ (r >> 3)) & 7);
        af[f] = *(const bf16x8*)&As[ul * 1024 + rs * 8];
      }
#pragma unroll
      for (int f = 0; f < 8; ++f) {
        int c = cw * 128 + f * 16 + m16;
        bfr[f] = *(const bf16x8*)&Bs[(ul * 256 + c) * 8];
      }
#pragma unroll
      for (int fi = 0; fi < 4; ++fi)
#pragma unroll
        for (int fj = 0; fj < 8; ++fj)
          acc[fi][fj] = __builtin_amdgcn_mfma_f32_16x16x32_bf16(
              af[fi], bfr[fj], acc[fi][fj], 0, 0, 0);
    }
    __syncthreads();  // LDS free for next tile's writes
  }

  float biasv[8];
#pragma unroll
  for (int fj = 0; fj < 8; ++fj) biasv[fj] = bias[cw * 128 + fj * 16 + m16];

#pragma unroll
  for (int fi = 0; fi < 4; ++fi) {
#pragma unroll
    for (int fj = 0; fj < 8; ++fj) {
      int col = cw * 128 + fj * 16 + m16;
      f32x4 v = acc[fi][fj];
#pragma unroll
      for (int i = 0; i < 4; ++i) {
        int rt = rw * 64 + fi * 16 + quad * 4 + i;
        int yo = yh * 8 + (rt >> 4);  // output pixel (16x16 grid)
        int xo = rt & 15;
        float val = fmaxf(v[i] + biasv[fj], 0.f);
        size_t addr = ((size_t)n << 16) + ((size_t)(yo >> 1) << 13) +
                      ((size_t)(xo >> 1) << 10) +
                      ((((yo & 1) << 1) | (xo & 1)) << 8) + col;
        Out[addr] = f2bf(val);
      }
    }
  }
}

// --------------------------- 64x256 dbuf GEMM (layer 1) ---------------------
// C[M x 256] = A[M x K] * Bt[256 x K]^T + bias, ReLU, bf16 out in patch-Z.
// Tile 64 x 256, BK=64, 4 waves each own a 64-col quarter over all 64 rows
// (acc[4][4]). Double-buffered LDS (80 KB): issue stage of kt+1 into buf^1,
// compute kt, then one __syncthreads() per K-step.
__global__ __launch_bounds__(256, 2) void gemm64_kernel(
    const unsigned short* __restrict__ A, const unsigned short* __restrict__ Bt,
    const float* __restrict__ bias, unsigned short* __restrict__ Out, int K,
    int hw_shift, int wsh) {
  __shared__ __align__(16) unsigned short As[2][64 * 64];    // 16 KB
  __shared__ __align__(16) unsigned short Bs[2][256 * 64];   // 64 KB
  const int t = threadIdx.x;
  const int lane = t & 63, wave = t >> 6;
  const int R0 = blockIdx.x * 64;
  const int m16 = lane & 15, quad = lane >> 4;

  const unsigned short* ga[2];
  const unsigned short* gb[8];
#pragma unroll
  for (int p = 0; p < 2; ++p) {
    int g = p * 256 + t;
    int r = g >> 3, u = g & 7;
    ga[p] = A + (size_t)(R0 + r) * K + ((u ^ (r & 7)) << 3);
  }
#pragma unroll
  for (int p = 0; p < 8; ++p) {
    int g = p * 256 + t;
    int r = g >> 3, u = g & 7;
    gb[p] = Bt + (size_t)r * K + ((u ^ (r & 7)) << 3);
  }

  const f32x4 zero = {0.f, 0.f, 0.f, 0.f};
  f32x4 acc[4][4];
#pragma unroll
  for (int i = 0; i < 4; ++i)
#pragma unroll
    for (int j = 0; j < 4; ++j) acc[i][j] = zero;

  const int kIters = K >> 6;
  // prologue: stage kt=0 -> buf0
#pragma unroll
  for (int p = 0; p < 2; ++p) async16(ga[p], &As[0][(p * 256 + t) * 8]);
#pragma unroll
  for (int p = 0; p < 8; ++p) async16(gb[p], &Bs[0][(p * 256 + t) * 8]);
  __syncthreads();

  for (int kt = 0; kt < kIters; ++kt) {
    const int cur = kt & 1;
    if (kt + 1 < kIters) {  // prefetch next K-tile into the other buffer
#pragma unroll
      for (int p = 0; p < 2; ++p)
        async16(ga[p] + (kt + 1) * 64, &As[cur ^ 1][(p * 256 + t) * 8]);
#pragma unroll
      for (int p = 0; p < 8; ++p)
        async16(gb[p] + (kt + 1) * 64, &Bs[cur ^ 1][(p * 256 + t) * 8]);
    }
#pragma unroll
    for (int ks = 0; ks < 2; ++ks) {
      bf16x8 af[4], bfr[4];
      int ul = (ks << 2) + quad;
#pragma unroll
      for (int f = 0; f < 4; ++f) {
        int ra = f * 16 + m16;
        af[f] = *(const bf16x8*)&As[cur][ra * 64 + ((ul ^ (ra & 7)) << 3)];
      }
#pragma unroll
      for (int f = 0; f < 4; ++f) {
        int rb = wave * 64 + f * 16 + m16;
        bfr[f] = *(const bf16x8*)&Bs[cur][rb * 64 + ((ul ^ (rb & 7)) << 3)];
      }
#pragma unroll
      for (int fi = 0; fi < 4; ++fi)
#pragma unroll
        for (int fj = 0; fj < 4; ++fj)
          acc[fi][fj] = __builtin_amdgcn_mfma_f32_16x16x32_bf16(
              af[fi], bfr[fj], acc[fi][fj], 0, 0, 0);
    }
    __syncthreads();  // drains prefetch (needed next iter) + guards buf reuse
  }

  float biasv[4];
#pragma unroll
  for (int fj = 0; fj < 4; ++fj) biasv[fj] = bias[wave * 64 + fj * 16 + m16];

#pragma unroll
  for (int fi = 0; fi < 4; ++fi) {
#pragma unroll
    for (int fj = 0; fj < 4; ++fj) {
      int col = wave * 64 + fj * 16 + m16;
      f32x4 v = acc[fi][fj];
#pragma unroll
      for (int i = 0; i < 4; ++i) {
        int R = R0 + fi * 16 + quad * 4 + i;
        float val = fmaxf(v[i] + biasv[fj], 0.f);
        int n = R >> hw_shift;
        int rem = R & ((1 << hw_shift) - 1);
        int y = rem >> wsh;
        int x = rem & ((1 << wsh) - 1);
        int q2 = ((y & 1) << 1) | (x & 1);
        size_t addr = ((size_t)n << (hw_shift + 8)) +
                      ((size_t)(y >> 1) << (wsh + 9)) +
                      ((size_t)(x >> 1) << 10) + (q2 << 8) + col;
        Out[addr] = f2bf(val);
      }
    }
  }
}

// --------------------------- megatail: layers 2+3+4 + fuse ------------------
// Grid 32 x 256, 1 block/CU. Block bh owns images [8bh, 8bh+8):
//   layer2 rows [128bh,+128) (two 64-row dbuf passes, A from inter1),
//   layer3 [32bh,+32) (A = C2s), layer4 [8bh,+8) (A = C3s), fuse (A = C4s).
// C-buffers stored in next-layer A layout: patch-Z local row * 1024 +
// XOR-8-swizzled 16B units -> ds_read_b128 A-frags, conflict-free.
// LDS: Bs dbuf 64K + As dbuf 16K (aliased as C3s) + C2s 64K + C4s 4K = 148K.
__global__ __launch_bounds__(256, 1) void megatail_kernel(
    const unsigned short* __restrict__ A2,      // inter1 [4096 x 1024]
    const unsigned short* __restrict__ Bt_all,  // conv weights (all layers)
    const float* __restrict__ bias_all,
    const unsigned short* __restrict__ Btf,     // fuse weights [256 x 256]
    const float* __restrict__ fbias,
    float* __restrict__ hbuf) {
  __shared__ __align__(16) unsigned short Bs[2][16384];  // 64 KB
  __shared__ __align__(16) unsigned short As[2][4096];   // 16 KB (later C3s)
  __shared__ __align__(16) unsigned short C2s[32768];    // 64 KB
  __shared__ __align__(16) unsigned short C4s[2048];     // 4 KB
  unsigned short* C3s = &As[0][0];                       // 8 rows x 1024
  const int t = threadIdx.x;
  const int lane = t & 63, wave = t >> 6;
  const int bh = blockIdx.x;
  const int m16 = lane & 15, quad = lane >> 4;
  const f32x4 zero = {0.f, 0.f, 0.f, 0.f};

  const unsigned short* Bt2 = Bt_all + 2 * 262144;
  const unsigned short* Bt3 = Bt_all + 3 * 262144;
  const unsigned short* Bt4 = Bt_all + 4 * 262144;

  // ---------------- layer 2: two 64-row dbuf passes ----------------
  for (int p = 0; p < 2; ++p) {
    const int R0 = bh * 128 + p * 64;
    const unsigned short* ga[2];
    const unsigned short* gb[8];
#pragma unroll
    for (int q = 0; q < 2; ++q) {
      int g = q * 256 + t;
      int r = g >> 3, u = g & 7;
      ga[q] = A2 + (size_t)(R0 + r) * 1024 + ((u ^ (r & 7)) << 3);
    }
#pragma unroll
    for (int q = 0; q < 8; ++q) {
      int g = q * 256 + t;
      int r = g >> 3, u = g & 7;
      gb[q] = Bt2 + (size_t)r * 1024 + ((u ^ (r & 7)) << 3);
    }
    f32x4 acc[4][4];
#pragma unroll
    for (int i = 0; i < 4; ++i)
#pragma unroll
      for (int j = 0; j < 4; ++j) acc[i][j] = zero;
#pragma unroll
    for (int q = 0; q < 2; ++q) async16(ga[q], &As[0][(q * 256 + t) * 8]);
#pragma unroll
    for (int q = 0; q < 8; ++q) async16(gb[q], &Bs[0][(q * 256 + t) * 8]);
    __syncthreads();
    for (int kt = 0; kt < 16; ++kt) {
      const int cur = kt & 1;
      if (kt < 15) {
#pragma unroll
        for (int q = 0; q < 2; ++q)
          async16(ga[q] + (kt + 1) * 64, &As[cur ^ 1][(q * 256 + t) * 8]);
#pragma unroll
        for (int q = 0; q < 8; ++q)
          async16(gb[q] + (kt + 1) * 64, &Bs[cur ^ 1][(q * 256 + t) * 8]);
      }
#pragma unroll
      for (int ks = 0; ks < 2; ++ks) {
        bf16x8 af[4], bfr[4];
        int ul = (ks << 2) + quad;
#pragma unroll
        for (int f = 0; f < 4; ++f) {
          int ra = f * 16 + m16;
          af[f] = *(const bf16x8*)&As[cur][ra * 64 + ((ul ^ (ra & 7)) << 3)];
        }
#pragma unroll
        for (int f = 0; f < 4; ++f) {
          int rb = wave * 64 + f * 16 + m16;
          bfr[f] = *(const bf16x8*)&Bs[cur][rb * 64 + ((ul ^ (rb & 7)) << 3)];
        }
#pragma unroll
        for (int fi = 0; fi < 4; ++fi)
#pragma unroll
          for (int fj = 0; fj < 4; ++fj)
            acc[fi][fj] = __builtin_amdgcn_mfma_f32_16x16x32_bf16(
                af[fi], bfr[fj], acc[fi][fj], 0, 0, 0);
      }
      __syncthreads();
    }
    // epilogue -> C2s (layer3-A layout; res 4x4: n=R>>4, y=(R>>2)&3, x=R&3)
    {
      float bv[4];
#pragma unroll
      for (int fj = 0; fj < 4; ++fj)
        bv[fj] = bias_all[512 + wave * 64 + fj * 16 + m16];
#pragma unroll
      for (int fi = 0; fi < 4; ++fi) {
#pragma unroll
        for (int fj = 0; fj < 4; ++fj) {
          int col = wave * 64 + fj * 16 + m16;
          f32x4 v = acc[fi][fj];
#pragma unroll
          for (int i = 0; i < 4; ++i) {
            int R2l = p * 64 + fi * 16 + quad * 4 + i;  // 0..127
            int nl = R2l >> 4;
            int y = (R2l >> 2) & 3, x = R2l & 3;
            int q2 = ((y & 1) << 1) | (x & 1);
            int P = nl * 4 + ((y >> 1) << 1) + (x >> 1);  // layer3 local row
            int k = (q2 << 8) + col;
            C2s[P * 1024 + (((k >> 3) ^ (P & 7)) << 3) + (k & 7)] =
                f2bf(fmaxf(v[i] + bv[fj], 0.f));
          }
        }
      }
    }
    __syncthreads();
  }

  // ---------------- layer 3: 32 rows, A = C2s, B dbuf ----------------
  {
    const unsigned short* gb[8];
#pragma unroll
    for (int q = 0; q < 8; ++q) {
      int g = q * 256 + t;
      int r = g >> 3, u = g & 7;
      gb[q] = Bt3 + (size_t)r * 1024 + ((u ^ (r & 7)) << 3);
    }
    f32x4 acc[2][4];
#pragma unroll
    for (int i = 0; i < 2; ++i)
#pragma unroll
      for (int j = 0; j < 4; ++j) acc[i][j] = zero;
#pragma unroll
    for (int q = 0; q < 8; ++q) async16(gb[q], &Bs[0][(q * 256 + t) * 8]);
    __syncthreads();
    for (int kt = 0; kt < 16; ++kt) {
      const int cur = kt & 1;
      if (kt < 15) {
#pragma unroll
        for (int q = 0; q < 8; ++q)
          async16(gb[q] + (kt + 1) * 64, &Bs[cur ^ 1][(q * 256 + t) * 8]);
      }
#pragma unroll
      for (int ks = 0; ks < 2; ++ks) {
        bf16x8 af[2], bfr[4];
        int ul = (ks << 2) + quad;
#pragma unroll
        for (int f = 0; f < 2; ++f) {
          int ra = f * 16 + m16;
          af[f] = *(const bf16x8*)&C2s[ra * 1024 +
                                       ((kt * 8 + (ul ^ (ra & 7))) << 3)];
        }
#pragma unroll
        for (int f = 0; f < 4; ++f) {
          int rb = wave * 64 + f * 16 + m16;
          bfr[f] = *(const bf16x8*)&Bs[cur][rb * 64 + ((ul ^ (rb & 7)) << 3)];
        }
#pragma unroll
        for (int fi = 0; fi < 2; ++fi)
#pragma unroll
          for (int fj = 0; fj < 4; ++fj)
            acc[fi][fj] = __builtin_amdgcn_mfma_f32_16x16x32_bf16(
                af[fi], bfr[fj], acc[fi][fj], 0, 0, 0);
      }
      __syncthreads();
    }
    // epilogue -> C3s (=As region; res 2x2: n=R>>2, q2=R&3)
    {
      float bv[4];
#pragma unroll
      for (int fj = 0; fj < 4; ++fj)
        bv[fj] = bias_all[768 + wave * 64 + fj * 16 + m16];
#pragma unroll
      for (int fi = 0; fi < 2; ++fi) {
#pragma unroll
        for (int fj = 0; fj < 4; ++fj) {
          int col = wave * 64 + fj * 16 + m16;
          f32x4 v = acc[fi][fj];
#pragma unroll
          for (int i = 0; i < 4; ++i) {
            int R3l = fi * 16 + quad * 4 + i;  // 0..31
            int nl = R3l >> 2;
            int k = ((R3l & 3) << 8) + col;
            C3s[nl * 1024 + (((k >> 3) ^ (nl & 7)) << 3) + (k & 7)] =
                f2bf(fmaxf(v[i] + bv[fj], 0.f));
          }
        }
      }
    }
  }
  __syncthreads();

  // ---------------- layer 4: 8 rows (A rows clamped to 8), A = C3s ---------
  {
    const unsigned short* gb[8];
#pragma unroll
    for (int q = 0; q < 8; ++q) {
      int g = q * 256 + t;
      int r = g >> 3, u = g & 7;
      gb[q] = Bt4 + (size_t)r * 1024 + ((u ^ (r & 7)) << 3);
    }
    f32x4 acc4[4];
#pragma unroll
    for (int j = 0; j < 4; ++j) acc4[j] = zero;
#pragma unroll
    for (int q = 0; q < 8; ++q) async16(gb[q], &Bs[0][(q * 256 + t) * 8]);
    __syncthreads();
    for (int kt = 0; kt < 16; ++kt) {
      const int cur = kt & 1;
      if (kt < 15) {
#pragma unroll
        for (int q = 0; q < 8; ++q)
          async16(gb[q] + (kt + 1) * 64, &Bs[cur ^ 1][(q * 256 + t) * 8]);
      }
#pragma unroll
      for (int ks = 0; ks < 2; ++ks) {
        int ul = (ks << 2) + quad;
        int ra = m16 & 7;  // rows 8..15 duplicate 0..7 (discarded on write)
        bf16x8 af =
            *(const bf16x8*)&C3s[ra * 1024 + ((kt * 8 + (ul ^ ra)) << 3)];
        bf16x8 bfr[4];
#pragma unroll
        for (int f = 0; f < 4; ++f) {
          int rb = wave * 64 + f * 16 + m16;
          bfr[f] = *(const bf16x8*)&Bs[cur][rb * 64 + ((ul ^ (rb & 7)) << 3)];
        }
#pragma unroll
        for (int fj = 0; fj < 4; ++fj)
          acc4[fj] = __builtin_amdgcn_mfma_f32_16x16x32_bf16(
              af, bfr[fj], acc4[fj], 0, 0, 0);
      }
      __syncthreads();
    }
    // epilogue -> C4s rows 0..7 (fuse-A layout, K=256)
    {
      float bv[4];
#pragma unroll
      for (int fj = 0; fj < 4; ++fj)
        bv[fj] = bias_all[1024 + wave * 64 + fj * 16 + m16];
#pragma unroll
      for (int fj = 0; fj < 4; ++fj) {
        int col = wave * 64 + fj * 16 + m16;
        f32x4 v = acc4[fj];
#pragma unroll
        for (int i = 0; i < 4; ++i) {
          if (quad < 2) {
            int R4 = quad * 4 + i;  // 0..7
            C4s[R4 * 256 + (((col >> 3) ^ R4) << 3) + (col & 7)] =
                f2bf(fmaxf(v[i] + bv[fj], 0.f));
          }
        }
      }
    }
  }
  __syncthreads();

  // ---------------- fuse: 8 rows, K=256 (4 kt), A = C4s --------------------
  {
    const unsigned short* gf[8];
#pragma unroll
    for (int q = 0; q < 8; ++q) {
      int g = q * 256 + t;
      int r = g >> 3, u = g & 7;
      gf[q] = Btf + (size_t)r * 256 + ((u ^ (r & 7)) << 3);
    }
    f32x4 acc4[4];
#pragma unroll
    for (int j = 0; j < 4; ++j) acc4[j] = zero;
#pragma unroll
    for (int q = 0; q < 8; ++q) async16(gf[q], &Bs[0][(q * 256 + t) * 8]);
    __syncthreads();
    for (int kt = 0; kt < 4; ++kt) {
      const int cur = kt & 1;
      if (kt < 3) {
#pragma unroll
        for (int q = 0; q < 8; ++q)
          async16(gf[q] + (kt + 1) * 64, &Bs[cur ^ 1][(q * 256 + t) * 8]);
      }
#pragma unroll
      for (int ks = 0; ks < 2; ++ks) {
        int ul = (ks << 2) + quad;
        int ra = m16 & 7;
        bf16x8 af =
            *(const bf16x8*)&C4s[ra * 256 + ((kt * 8 + (ul ^ ra)) << 3)];
        bf16x8 bfr[4];
#pragma unroll
        for (int f = 0; f < 4; ++f) {
          int rb = wave * 64 + f * 16 + m16;
          bfr[f] = *(const bf16x8*)&Bs[cur][rb * 64 + ((ul ^ (rb & 7)) << 3)];
        }
#pragma unroll
        for (int fj = 0; fj < 4; ++fj)
          acc4[fj] = __builtin_amdgcn_mfma_f32_16x16x32_bf16(
              af, bfr[fj], acc4[fj], 0, 0, 0);
      }
      __syncthreads();
    }
    // epilogue: f32 -> hbuf rows [8bh, 8bh+8), no ReLU
    {
      float fb[4];
#pragma unroll
      for (int fj = 0; fj < 4; ++fj)
        fb[fj] = fbias[wave * 64 + fj * 16 + m16];
#pragma unroll
      for (int fj = 0; fj < 4; ++fj) {
        int col = wave * 64 + fj * 16 + m16;
        f32x4 v = acc4[fj];
#pragma unroll
        for (int i = 0; i < 4; ++i) {
          if (quad < 2) {
            int R = bh * 8 + quad * 4 + i;
            hbuf[((size_t)R << 8) + col] = v[i] + fb[fj];
          }
        }
      }
    }
  }
}

// --------------------------- FFT + gate logits (+finalize) ------------------
// Last block (elected via device-scope atomic on a prep-zeroed counter)
// performs the top-k gates + load computation. Agent-scope __threadfence()
// provides the cross-XCD L2 writeback/invalidate.
__global__ void fft_gate_kernel(const float* __restrict__ hbuf,
                                const float* __restrict__ w_gate,
                                float* __restrict__ weights,
                                int* __restrict__ counter,
                                float* __restrict__ out) {
  __shared__ float cs[32], sn[32];
  __shared__ float wg[144];
  __shared__ float red[4][9];
  __shared__ int rank;
  const int b = blockIdx.x, t = threadIdx.x;
  if (t < 32) {
    float ang = 6.283185307179586f * (float)t / 32.0f;
    cs[t] = cosf(ang);
    sn[t] = sinf(ang);
  }
  if (t < 144) wg[t] = w_gate[t];
  __syncthreads();

  float hl[32];
#pragma unroll
  for (int tt = 0; tt < 32; ++tt) hl[tt] = hbuf[(size_t)(b * 32 + tt) * 256 + t];

  float lg[9];
#pragma unroll
  for (int s = 0; s < 9; ++s) lg[s] = 0.f;

#pragma unroll
  for (int f = 1; f <= 16; ++f) {
    float re = 0.f, im = 0.f;
#pragma unroll
    for (int tt = 0; tt < 32; ++tt) {
      int idx = (f * tt) & 31;
      re += hl[tt] * cs[idx];
      im += hl[tt] * sn[idx];
    }
    float amp = sqrtf(re * re + im * im) * 0.17677669529663687f;  // 1/sqrt(32)
#pragma unroll
    for (int s = 0; s < 9; ++s) lg[s] += amp * wg[(f - 1) * 9 + s];
  }

  const int lane = t & 63, wave = t >> 6;
#pragma unroll
  for (int s = 0; s < 9; ++s) {
    float v = lg[s];
    v += __shfl_down(v, 32, 64);
    v += __shfl_down(v, 16, 64);
    v += __shfl_down(v, 8, 64);
    v += __shfl_down(v, 4, 64);
    v += __shfl_down(v, 2, 64);
    v += __shfl_down(v, 1, 64);
    if (lane == 0) red[wave][s] = v;
  }
  __syncthreads();
  if (t < 9) {
    float total = red[0][t] + red[1][t] + red[2][t] + red[3][t];
    weights[b * 9 + t] = total * (1.0f / 256.0f);
  }
  __syncthreads();  // weights stores drained (vmcnt) for all threads
  if (t == 0) {
    __threadfence();               // release: write back L2 to coherent point
    rank = atomicAdd(counter, 1);  // device-scope
  }
  __syncthreads();
  if (rank == 7) {  // last block finalizes (uniform branch)
    __threadfence();  // acquire: invalidate stale cached lines
    if (t < 8) {
      float w[9];
      int idx[9];
#pragma unroll
      for (int s = 0; s < 9; ++s) {
        w[s] = weights[t * 9 + s];
        idx[s] = s;
      }
      for (int a = 0; a < 4; ++a) {
        int best = a;
        for (int c = a + 1; c < 9; ++c)
          if (w[idx[c]] > w[idx[best]]) best = c;
        int tmp = idx[a];
        idx[a] = idx[best];
        idx[best] = tmp;
      }
      float m = w[idx[0]];
      float e0 = expf(w[idx[0]] - m);
      float e1 = expf(w[idx[1]] - m);
      float e2 = expf(w[idx[2]] - m);
      float inv = 1.0f / (e0 + e1 + e2);
      float g[9];
#pragma unroll
      for (int s = 0; s < 9; ++s) g[s] = 0.f;
      g[idx[0]] = e0 * inv;
      g[idx[1]] = e1 * inv;
      g[idx[2]] = e2 * inv;
#pragma unroll
      for (int s = 0; s < 9; ++s) out[t * 9 + s] = g[s];
    }
    __syncthreads();
    if (t < 9) {
      int cnt = 0;
#pragma unroll
      for (int b2 = 0; b2 < 8; ++b2) cnt += (out[b2 * 9 + t] > 0.f) ? 1 : 0;
      out[72 + t] = (float)cnt;
    }
  }
}

// --------------------------- launch ----------------------------------------
extern "C" void kernel_launch(void* const* d_in, const int* in_sizes, int n_in,
                              void* d_out, int out_size, void* d_ws,
                              size_t ws_size, hipStream_t stream) {
  (void)in_sizes; (void)n_in; (void)out_size; (void)ws_size;
  const float* x      = (const float*)d_in[0];
  const float* conv_w = (const float*)d_in[1];
  const float* conv_b = (const float*)d_in[2];
  const float* gamma  = (const float*)d_in[3];
  const float* beta   = (const float*)d_in[4];
  const float* mean   = (const float*)d_in[5];
  const float* var    = (const float*)d_in[6];
  const float* fuse_w = (const float*)d_in[7];
  const float* fuse_b = (const float*)d_in[8];
  const float* w_gate = (const float*)d_in[9];

  char* ws = (char*)d_ws;
  size_t off = 0;
  auto alloc = [&](size_t bytes) {
    void* p = ws + off;
    off = (off + bytes + 255) & ~(size_t)255;
    return p;
  };
  unsigned short* Bt_all  = (unsigned short*)alloc((size_t)5 * 262144 * 2);
  unsigned short* Bt_fuse = (unsigned short*)alloc((size_t)65536 * 2);
  float* bias_all         = (float*)alloc(1280 * 4);
  unsigned short* inter0  = (unsigned short*)alloc((size_t)65536 * 256 * 2);
  unsigned short* inter1  = (unsigned short*)alloc((size_t)16384 * 256 * 2);
  float* hbuf             = (float*)alloc((size_t)256 * 256 * 4);
  float* wts              = (float*)alloc(72 * 4);
  int* counter            = (int*)alloc(4);

  prep_kernel<<<5382, 256, 0, stream>>>(conv_w, conv_b, gamma, beta, mean, var,
                                        fuse_w, Bt_all, Bt_fuse, bias_all,
                                        counter);
  layer0_kernel<<<512, 256, 0, stream>>>(x, Bt_all, bias_all, inter0);
  gemm64_kernel<<<256, 256, 0, stream>>>(
      inter0, Bt_all + 262144, bias_all + 256, inter1, 1024, 6, 3);
  megatail_kernel<<<32, 256, 0, stream>>>(inter1, Bt_all, bias_all, Bt_fuse,
                                          fuse_b, hbuf);
  fft_gate_kernel<<<8, 256, 0, stream>>>(hbuf, w_gate, wts, counter,
                                         (float*)d_out);
}

// Round 4
// 512.376 us; speedup vs baseline: 1.1195x; 1.0251x over previous
//
#include <hip/hip_runtime.h>
#include <stdint.h>

// ---------------------------------------------------------------------------
// FourierLayer: 5x [conv2x2s2 + BN(eval) + ReLU] -> fuse proj -> rFFT(32) ->
// gating (top-3 softmax) on MI355X.
//
// Pipeline (5 dispatches):
//   prep -> layer0 (fused im2col GEMM, HBM-bound ~41us floor)
//        -> gemm64 (layer1, 256 blocks, dbuf)
//        -> megatail v2 (layers 2+3+4+fuse, grid 64, BARRIER-FREE K-loops)
//        -> fft_gate (+fused finalize via last-block elect)
//
// megatail v2: block bh owns images [4bh,4bh+4) -> layer2 rows [64bh,+64),
// layer3 [16bh,+16), layer4/fuse [4bh,+4). K-loops are barrier-free: A and B
// fragments load directly global->VGPR (B has zero in-block reuse; A's 4x
// redundant fetch is cheap L2 traffic), offsets fold into the 13-bit global
// load immediate. Only inter-layer intermediates go through LDS (C2s 32K,
// C3s 8K, C4s 2K), XOR-8 swizzled; one barrier per layer boundary. MFMA
// (kt,ks) accumulation order identical -> bitwise-identical outputs.
// ---------------------------------------------------------------------------

typedef __attribute__((ext_vector_type(8))) short bf16x8;
typedef __attribute__((ext_vector_type(4))) float f32x4;

#define DEV __device__ __forceinline__
#define GLOBAL_AS __attribute__((address_space(1)))
#define LDS_AS __attribute__((address_space(3)))

DEV unsigned short f2bf(float f) {
  union { float f; uint32_t u; } v; v.f = f;
  uint32_t u = v.u;
  return (unsigned short)((u + 0x7fffu + ((u >> 16) & 1u)) >> 16);
}

DEV void async16(const void* g, void* l) {
  __builtin_amdgcn_global_load_lds((GLOBAL_AS void*)g, (LDS_AS void*)l, 16, 0, 0);
}

// --------------------------- weight prep ----------------------------------
// idx < 262144: layer0 B image [kt(16)][u(8)][c(256)][kv(8)], k=q*16+ci_l,
//               u=k>>3 (q=u>>1, ci_l=(u&1)*8+kv), ci=kt*16+ci_l.
// else l=1..4:  Bt[l][co][k=q*256+ci] (patch-Z A order). Then Bt_fuse, bias,
// and the fft_gate election counter (zeroed each iteration).
__global__ void prep_kernel(const float* __restrict__ conv_w,
                            const float* __restrict__ conv_b,
                            const float* __restrict__ gamma,
                            const float* __restrict__ beta,
                            const float* __restrict__ mean,
                            const float* __restrict__ var,
                            const float* __restrict__ fuse_w,
                            unsigned short* __restrict__ Bt_all,
                            unsigned short* __restrict__ Bt_fuse,
                            float* __restrict__ bias_all,
                            int* __restrict__ counter) {
  int idx = blockIdx.x * 256 + threadIdx.x;
  const int NB = 5 * 256 * 1024;
  if (idx < 262144) {
    int kv = idx & 7;
    int c = (idx >> 3) & 255;
    int u = (idx >> 11) & 7;
    int kt = idx >> 14;
    int q = u >> 1;
    int ci = kt * 16 + (u & 1) * 8 + kv;
    float scale = gamma[c] * rsqrtf(var[c] + 1e-5f);
    Bt_all[idx] = f2bf(conv_w[(((size_t)c * 256 + ci) << 2) + q] * scale);
  } else if (idx < NB) {
    int l = idx >> 18;  // 1..4
    int rem = idx & 262143;
    int co = rem >> 10;
    int k = rem & 1023;
    int q = k >> 8;
    int ci = k & 255;
    int lc = l * 256 + co;
    float scale = gamma[lc] * rsqrtf(var[lc] + 1e-5f);
    Bt_all[idx] = f2bf(conv_w[(((size_t)lc * 256 + ci) << 2) + q] * scale);
  } else if (idx < NB + 65536) {
    int i = idx - NB;
    Bt_fuse[i] = f2bf(fuse_w[i]);
  } else if (idx < NB + 65536 + 1280) {
    int j = idx - (NB + 65536);
    float scale = gamma[j] * rsqrtf(var[j] + 1e-5f);
    bias_all[j] = (conv_b[j] - mean[j]) * scale + beta[j];
  } else if (idx == NB + 65536 + 1280) {
    *counter = 0;
  }
}

// --------------------------- layer 0 (fused im2col GEMM) --------------------
// Block = (n = blk>>1, yh = blk&1): rows r = (Yl>>1)*16 + xp, Yl in [0,16),
// Y_img = yh*16 + Yl. K-tile kt: ci in [kt*16, kt*16+16), all 4 q.
// As: [u(8)][rsw(128)][kv(8)] bf16, rsw = (r&0x78)|((r^(r>>3))&7).
// Bs: [u(8)][c(256)][kv(8)] bf16, staged contiguously via async16.
__global__ __launch_bounds__(256, 2) void layer0_kernel(
    const float* __restrict__ X, const unsigned short* __restrict__ Bt0,
    const float* __restrict__ bias, unsigned short* __restrict__ Out) {
  __shared__ __align__(16) unsigned short As[8192];
  __shared__ __align__(16) unsigned short Bs[16384];
  const int t = threadIdx.x;
  const int lane = t & 63, wave = t >> 6;
  const int n = blockIdx.x >> 1, yh = blockIdx.x & 1;
  const int m16 = lane & 15, quad = lane >> 4;
  const int rw = wave >> 1, cw = wave & 1;
  const int xq = lane & 7, ci_lo = lane >> 3;  // ci varies within wave
  const float* xn = X + (size_t)n * 262144 + (size_t)(yh * 16) * 32;

  const f32x4 zero = {0.f, 0.f, 0.f, 0.f};
  f32x4 acc[4][8];
#pragma unroll
  for (int i = 0; i < 4; ++i)
#pragma unroll
    for (int j = 0; j < 8; ++j) acc[i][j] = zero;

  for (int kt = 0; kt < 16; ++kt) {
    // B stage: 32 KB contiguous
#pragma unroll
    for (int i = 0; i < 8; ++i)
      async16(Bt0 + (size_t)kt * 16384 + (i * 256 + t) * 8,
              &Bs[(i * 256 + t) * 8]);
    // A stage: 8 float4 loads -> 32 bf16 scattered writes
#pragma unroll
    for (int j = 0; j < 8; ++j) {
      int Yl = wave * 4 + (j & 3);
      int ci_l = (j >> 2) * 8 + ci_lo;
      int ci = kt * 16 + ci_l;
      const float4 f = *(const float4*)(xn + (size_t)ci * 1024 + Yl * 32 + xq * 4);
      int qY = (Yl & 1) * 2;
      int rb = (Yl >> 1) * 16 + xq * 2;
      int cihi = ci_l >> 3, kv = ci_l & 7;
      int u0 = qY * 2 + cihi;
      int r0s = (rb & 0x78) | ((rb ^ (rb >> 3)) & 7);
      int r1 = rb + 1;
      int r1s = (r1 & 0x78) | ((r1 ^ (r1 >> 3)) & 7);
      As[u0 * 1024 + r0s * 8 + kv] = f2bf(f.x);
      As[(u0 + 2) * 1024 + r0s * 8 + kv] = f2bf(f.y);
      As[u0 * 1024 + r1s * 8 + kv] = f2bf(f.z);
      As[(u0 + 2) * 1024 + r1s * 8 + kv] = f2bf(f.w);
    }
    __syncthreads();  // drains async16 (vmcnt) + ds writes
#pragma unroll
    for (int ks = 0; ks < 2; ++ks) {
      bf16x8 af[4], bfr[8];
      int ul = ks * 4 + quad;
#pragma unroll
      for (int f = 0; f < 4; ++f) {
        int r = rw * 64 + f * 16 + m16;
        int rs = (r & 0x78) | ((r ^ (r >> 3)) & 7);
        af[f] = *(const bf16x8*)&As[ul * 1024 + rs * 8];
      }
#pragma unroll
      for (int f = 0; f < 8; ++f) {
        int c = cw * 128 + f * 16 + m16;
        bfr[f] = *(const bf16x8*)&Bs[(ul * 256 + c) * 8];
      }
#pragma unroll
      for (int fi = 0; fi < 4; ++fi)
#pragma unroll
        for (int fj = 0; fj < 8; ++fj)
          acc[fi][fj] = __builtin_amdgcn_mfma_f32_16x16x32_bf16(
              af[fi], bfr[fj], acc[fi][fj], 0, 0, 0);
    }
    __syncthreads();  // LDS free for next tile's writes
  }

  float biasv[8];
#pragma unroll
  for (int fj = 0; fj < 8; ++fj) biasv[fj] = bias[cw * 128 + fj * 16 + m16];

#pragma unroll
  for (int fi = 0; fi < 4; ++fi) {
#pragma unroll
    for (int fj = 0; fj < 8; ++fj) {
      int col = cw * 128 + fj * 16 + m16;
      f32x4 v = acc[fi][fj];
#pragma unroll
      for (int i = 0; i < 4; ++i) {
        int rt = rw * 64 + fi * 16 + quad * 4 + i;
        int yo = yh * 8 + (rt >> 4);  // output pixel (16x16 grid)
        int xo = rt & 15;
        float val = fmaxf(v[i] + biasv[fj], 0.f);
        size_t addr = ((size_t)n << 16) + ((size_t)(yo >> 1) << 13) +
                      ((size_t)(xo >> 1) << 10) +
                      ((((yo & 1) << 1) | (xo & 1)) << 8) + col;
        Out[addr] = f2bf(val);
      }
    }
  }
}

// --------------------------- 64x256 dbuf GEMM (layer 1) ---------------------
// C[M x 256] = A[M x K] * Bt[256 x K]^T + bias, ReLU, bf16 out in patch-Z.
// Tile 64 x 256, BK=64, 4 waves each own a 64-col quarter over all 64 rows
// (acc[4][4]). Double-buffered LDS (80 KB): issue stage of kt+1 into buf^1,
// compute kt, then one __syncthreads() per K-step.
__global__ __launch_bounds__(256, 2) void gemm64_kernel(
    const unsigned short* __restrict__ A, const unsigned short* __restrict__ Bt,
    const float* __restrict__ bias, unsigned short* __restrict__ Out, int K,
    int hw_shift, int wsh) {
  __shared__ __align__(16) unsigned short As[2][64 * 64];    // 16 KB
  __shared__ __align__(16) unsigned short Bs[2][256 * 64];   // 64 KB
  const int t = threadIdx.x;
  const int lane = t & 63, wave = t >> 6;
  const int R0 = blockIdx.x * 64;
  const int m16 = lane & 15, quad = lane >> 4;

  const unsigned short* ga[2];
  const unsigned short* gb[8];
#pragma unroll
  for (int p = 0; p < 2; ++p) {
    int g = p * 256 + t;
    int r = g >> 3, u = g & 7;
    ga[p] = A + (size_t)(R0 + r) * K + ((u ^ (r & 7)) << 3);
  }
#pragma unroll
  for (int p = 0; p < 8; ++p) {
    int g = p * 256 + t;
    int r = g >> 3, u = g & 7;
    gb[p] = Bt + (size_t)r * K + ((u ^ (r & 7)) << 3);
  }

  const f32x4 zero = {0.f, 0.f, 0.f, 0.f};
  f32x4 acc[4][4];
#pragma unroll
  for (int i = 0; i < 4; ++i)
#pragma unroll
    for (int j = 0; j < 4; ++j) acc[i][j] = zero;

  const int kIters = K >> 6;
  // prologue: stage kt=0 -> buf0
#pragma unroll
  for (int p = 0; p < 2; ++p) async16(ga[p], &As[0][(p * 256 + t) * 8]);
#pragma unroll
  for (int p = 0; p < 8; ++p) async16(gb[p], &Bs[0][(p * 256 + t) * 8]);
  __syncthreads();

  for (int kt = 0; kt < kIters; ++kt) {
    const int cur = kt & 1;
    if (kt + 1 < kIters) {  // prefetch next K-tile into the other buffer
#pragma unroll
      for (int p = 0; p < 2; ++p)
        async16(ga[p] + (kt + 1) * 64, &As[cur ^ 1][(p * 256 + t) * 8]);
#pragma unroll
      for (int p = 0; p < 8; ++p)
        async16(gb[p] + (kt + 1) * 64, &Bs[cur ^ 1][(p * 256 + t) * 8]);
    }
#pragma unroll
    for (int ks = 0; ks < 2; ++ks) {
      bf16x8 af[4], bfr[4];
      int ul = (ks << 2) + quad;
#pragma unroll
      for (int f = 0; f < 4; ++f) {
        int ra = f * 16 + m16;
        af[f] = *(const bf16x8*)&As[cur][ra * 64 + ((ul ^ (ra & 7)) << 3)];
      }
#pragma unroll
      for (int f = 0; f < 4; ++f) {
        int rb = wave * 64 + f * 16 + m16;
        bfr[f] = *(const bf16x8*)&Bs[cur][rb * 64 + ((ul ^ (rb & 7)) << 3)];
      }
#pragma unroll
      for (int fi = 0; fi < 4; ++fi)
#pragma unroll
        for (int fj = 0; fj < 4; ++fj)
          acc[fi][fj] = __builtin_amdgcn_mfma_f32_16x16x32_bf16(
              af[fi], bfr[fj], acc[fi][fj], 0, 0, 0);
    }
    __syncthreads();  // drains prefetch (needed next iter) + guards buf reuse
  }

  float biasv[4];
#pragma unroll
  for (int fj = 0; fj < 4; ++fj) biasv[fj] = bias[wave * 64 + fj * 16 + m16];

#pragma unroll
  for (int fi = 0; fi < 4; ++fi) {
#pragma unroll
    for (int fj = 0; fj < 4; ++fj) {
      int col = wave * 64 + fj * 16 + m16;
      f32x4 v = acc[fi][fj];
#pragma unroll
      for (int i = 0; i < 4; ++i) {
        int R = R0 + fi * 16 + quad * 4 + i;
        float val = fmaxf(v[i] + biasv[fj], 0.f);
        int n = R >> hw_shift;
        int rem = R & ((1 << hw_shift) - 1);
        int y = rem >> wsh;
        int x = rem & ((1 << wsh) - 1);
        int q2 = ((y & 1) << 1) | (x & 1);
        size_t addr = ((size_t)n << (hw_shift + 8)) +
                      ((size_t)(y >> 1) << (wsh + 9)) +
                      ((size_t)(x >> 1) << 10) + (q2 << 8) + col;
        Out[addr] = f2bf(val);
      }
    }
  }
}

// --------------------------- megatail v2: layers 2+3+4 + fuse ---------------
// Grid 64 x 256. Block bh owns images [4bh,4bh+4): layer2 rows [64bh,+64),
// layer3 [16bh,+16), layer4 [4bh,+4), fuse [4bh,+4). Barrier-free K-loops:
// A/B fragments direct global->VGPR (offsets fold into 13-bit imm); LDS only
// for inter-layer intermediates (C2s/C3s/C4s, XOR-8 swizzled), one barrier
// per layer boundary. (kt,ks) MFMA order unchanged -> bitwise-identical.
__global__ __launch_bounds__(256, 1) void megatail_kernel(
    const unsigned short* __restrict__ A2,      // inter1 as [4096 x 1024]
    const unsigned short* __restrict__ Bt_all,  // conv weights (all layers)
    const float* __restrict__ bias_all,
    const unsigned short* __restrict__ Btf,     // fuse weights [256 x 256]
    const float* __restrict__ fbias,
    float* __restrict__ hbuf) {
  __shared__ __align__(16) unsigned short C2s[16 * 1024];  // 32 KB
  __shared__ __align__(16) unsigned short C3s[4 * 1024];   // 8 KB
  __shared__ __align__(16) unsigned short C4s[4 * 256];    // 2 KB
  const int t = threadIdx.x;
  const int lane = t & 63, wave = t >> 6;
  const int bh = blockIdx.x;
  const int m16 = lane & 15, quad = lane >> 4;
  const f32x4 zero = {0.f, 0.f, 0.f, 0.f};

  const unsigned short* Bt2 = Bt_all + 2 * 262144;
  const unsigned short* Bt3 = Bt_all + 3 * 262144;
  const unsigned short* Bt4 = Bt_all + 4 * 262144;

  // ---------------- layer 2: 64 rows, barrier-free ----------------
  {
    const unsigned short* aB[4];
    const unsigned short* bB[4];
#pragma unroll
    for (int f = 0; f < 4; ++f) {
      aB[f] = A2 + (size_t)(bh * 64 + f * 16 + m16) * 1024;
      bB[f] = Bt2 + (size_t)(wave * 64 + f * 16 + m16) * 1024;
    }
    f32x4 acc[4][4];
#pragma unroll
    for (int i = 0; i < 4; ++i)
#pragma unroll
      for (int j = 0; j < 4; ++j) acc[i][j] = zero;
#pragma unroll
    for (int kt = 0; kt < 16; ++kt) {
#pragma unroll
      for (int ks = 0; ks < 2; ++ks) {
        const int off = kt * 64 + ((ks << 2) + quad) * 8;
        bf16x8 af[4], bfr[4];
#pragma unroll
        for (int f = 0; f < 4; ++f) af[f] = *(const bf16x8*)(aB[f] + off);
#pragma unroll
        for (int f = 0; f < 4; ++f) bfr[f] = *(const bf16x8*)(bB[f] + off);
#pragma unroll
        for (int fi = 0; fi < 4; ++fi)
#pragma unroll
          for (int fj = 0; fj < 4; ++fj)
            acc[fi][fj] = __builtin_amdgcn_mfma_f32_16x16x32_bf16(
                af[fi], bfr[fj], acc[fi][fj], 0, 0, 0);
      }
    }
    // epilogue -> C2s (layer3-A layout; 4x4 image grid: n=R>>4, y,x in [0,4))
    float bv[4];
#pragma unroll
    for (int fj = 0; fj < 4; ++fj)
      bv[fj] = bias_all[512 + wave * 64 + fj * 16 + m16];
#pragma unroll
    for (int fi = 0; fi < 4; ++fi) {
#pragma unroll
      for (int fj = 0; fj < 4; ++fj) {
        int col = wave * 64 + fj * 16 + m16;
        f32x4 v = acc[fi][fj];
#pragma unroll
        for (int i = 0; i < 4; ++i) {
          int R2l = fi * 16 + quad * 4 + i;  // 0..63
          int nl = R2l >> 4;
          int y = (R2l >> 2) & 3, x = R2l & 3;
          int q2 = ((y & 1) << 1) | (x & 1);
          int P = nl * 4 + ((y >> 1) << 1) + (x >> 1);  // layer3 local row
          int k = (q2 << 8) + col;
          C2s[P * 1024 + (((k >> 3) ^ (P & 7)) << 3) + (k & 7)] =
              f2bf(fmaxf(v[i] + bv[fj], 0.f));
        }
      }
    }
  }
  __syncthreads();

  // ---------------- layer 3: 16 rows, A = C2s, barrier-free ----------------
  {
    const unsigned short* bB[4];
#pragma unroll
    for (int f = 0; f < 4; ++f)
      bB[f] = Bt3 + (size_t)(wave * 64 + f * 16 + m16) * 1024;
    f32x4 acc3[4];
#pragma unroll
    for (int j = 0; j < 4; ++j) acc3[j] = zero;
#pragma unroll
    for (int kt = 0; kt < 16; ++kt) {
#pragma unroll
      for (int ks = 0; ks < 2; ++ks) {
        const int ul = (ks << 2) + quad;
        const int off = kt * 64 + ul * 8;
        const int ra = m16;  // 0..15
        bf16x8 af =
            *(const bf16x8*)&C2s[ra * 1024 + ((kt * 8 + (ul ^ (ra & 7))) << 3)];
        bf16x8 bfr[4];
#pragma unroll
        for (int f = 0; f < 4; ++f) bfr[f] = *(const bf16x8*)(bB[f] + off);
#pragma unroll
        for (int fj = 0; fj < 4; ++fj)
          acc3[fj] = __builtin_amdgcn_mfma_f32_16x16x32_bf16(af, bfr[fj],
                                                             acc3[fj], 0, 0, 0);
      }
    }
    // epilogue -> C3s (layer4-A layout; rows quad*4+i, all 16 valid)
    float bv[4];
#pragma unroll
    for (int fj = 0; fj < 4; ++fj)
      bv[fj] = bias_all[768 + wave * 64 + fj * 16 + m16];
#pragma unroll
    for (int fj = 0; fj < 4; ++fj) {
      int col = wave * 64 + fj * 16 + m16;
      f32x4 v = acc3[fj];
#pragma unroll
      for (int i = 0; i < 4; ++i) {
        int R3l = quad * 4 + i;  // 0..15
        int nl = R3l >> 2;       // 0..3
        int k = ((R3l & 3) << 8) + col;
        C3s[nl * 1024 + (((k >> 3) ^ nl) << 3) + (k & 7)] =
            f2bf(fmaxf(v[i] + bv[fj], 0.f));
      }
    }
  }
  __syncthreads();

  // ---------------- layer 4: 4 rows, A = C3s, barrier-free -----------------
  {
    const unsigned short* bB[4];
#pragma unroll
    for (int f = 0; f < 4; ++f)
      bB[f] = Bt4 + (size_t)(wave * 64 + f * 16 + m16) * 1024;
    f32x4 acc4[4];
#pragma unroll
    for (int j = 0; j < 4; ++j) acc4[j] = zero;
#pragma unroll
    for (int kt = 0; kt < 16; ++kt) {
#pragma unroll
      for (int ks = 0; ks < 2; ++ks) {
        const int ul = (ks << 2) + quad;
        const int off = kt * 64 + ul * 8;
        const int ra = m16 & 3;  // rows 4..15 duplicate 0..3 (discarded)
        bf16x8 af =
            *(const bf16x8*)&C3s[ra * 1024 + ((kt * 8 + (ul ^ ra)) << 3)];
        bf16x8 bfr[4];
#pragma unroll
        for (int f = 0; f < 4; ++f) bfr[f] = *(const bf16x8*)(bB[f] + off);
#pragma unroll
        for (int fj = 0; fj < 4; ++fj)
          acc4[fj] = __builtin_amdgcn_mfma_f32_16x16x32_bf16(af, bfr[fj],
                                                             acc4[fj], 0, 0, 0);
      }
    }
    // epilogue -> C4s rows 0..3 (fuse-A layout, K=256)
    float bv[4];
#pragma unroll
    for (int fj = 0; fj < 4; ++fj)
      bv[fj] = bias_all[1024 + wave * 64 + fj * 16 + m16];
#pragma unroll
    for (int fj = 0; fj < 4; ++fj) {
      int col = wave * 64 + fj * 16 + m16;
      f32x4 v = acc4[fj];
#pragma unroll
      for (int i = 0; i < 4; ++i) {
        if (quad == 0) {
          int R4 = i;  // 0..3
          C4s[R4 * 256 + (((col >> 3) ^ R4) << 3) + (col & 7)] =
              f2bf(fmaxf(v[i] + bv[fj], 0.f));
        }
      }
    }
  }
  __syncthreads();

  // ---------------- fuse: 4 rows, K=256, A = C4s, barrier-free -------------
  {
    const unsigned short* bB[4];
#pragma unroll
    for (int f = 0; f < 4; ++f)
      bB[f] = Btf + (size_t)(wave * 64 + f * 16 + m16) * 256;
    f32x4 accf[4];
#pragma unroll
    for (int j = 0; j < 4; ++j) accf[j] = zero;
#pragma unroll
    for (int kt = 0; kt < 4; ++kt) {
#pragma unroll
      for (int ks = 0; ks < 2; ++ks) {
        const int ul = (ks << 2) + quad;
        const int off = kt * 64 + ul * 8;
        const int ra = m16 & 3;
        bf16x8 af = *(const bf16x8*)&C4s[ra * 256 + ((kt * 8 + (ul ^ ra)) << 3)];
        bf16x8 bfr[4];
#pragma unroll
        for (int f = 0; f < 4; ++f) bfr[f] = *(const bf16x8*)(bB[f] + off);
#pragma unroll
        for (int fj = 0; fj < 4; ++fj)
          accf[fj] = __builtin_amdgcn_mfma_f32_16x16x32_bf16(af, bfr[fj],
                                                             accf[fj], 0, 0, 0);
      }
    }
    // epilogue: f32 -> hbuf rows [4bh, 4bh+4), no ReLU
    float fb[4];
#pragma unroll
    for (int fj = 0; fj < 4; ++fj) fb[fj] = fbias[wave * 64 + fj * 16 + m16];
#pragma unroll
    for (int fj = 0; fj < 4; ++fj) {
      int col = wave * 64 + fj * 16 + m16;
      f32x4 v = accf[fj];
#pragma unroll
      for (int i = 0; i < 4; ++i) {
        if (quad == 0) {
          int R = bh * 4 + i;
          hbuf[((size_t)R << 8) + col] = v[i] + fb[fj];
        }
      }
    }
  }
}

// --------------------------- FFT + gate logits (+finalize) ------------------
// Last block (elected via device-scope atomic on a prep-zeroed counter)
// performs the top-k gates + load computation. Agent-scope __threadfence()
// provides the cross-XCD L2 writeback/invalidate.
__global__ void fft_gate_kernel(const float* __restrict__ hbuf,
                                const float* __restrict__ w_gate,
                                float* __restrict__ weights,
                                int* __restrict__ counter,
                                float* __restrict__ out) {
  __shared__ float cs[32], sn[32];
  __shared__ float wg[144];
  __shared__ float red[4][9];
  __shared__ int rank;
  const int b = blockIdx.x, t = threadIdx.x;
  if (t < 32) {
    float ang = 6.283185307179586f * (float)t / 32.0f;
    cs[t] = cosf(ang);
    sn[t] = sinf(ang);
  }
  if (t < 144) wg[t] = w_gate[t];
  __syncthreads();

  float hl[32];
#pragma unroll
  for (int tt = 0; tt < 32; ++tt) hl[tt] = hbuf[(size_t)(b * 32 + tt) * 256 + t];

  float lg[9];
#pragma unroll
  for (int s = 0; s < 9; ++s) lg[s] = 0.f;

#pragma unroll
  for (int f = 1; f <= 16; ++f) {
    float re = 0.f, im = 0.f;
#pragma unroll
    for (int tt = 0; tt < 32; ++tt) {
      int idx = (f * tt) & 31;
      re += hl[tt] * cs[idx];
      im += hl[tt] * sn[idx];
    }
    float amp = sqrtf(re * re + im * im) * 0.17677669529663687f;  // 1/sqrt(32)
#pragma unroll
    for (int s = 0; s < 9; ++s) lg[s] += amp * wg[(f - 1) * 9 + s];
  }

  const int lane = t & 63, wave = t >> 6;
#pragma unroll
  for (int s = 0; s < 9; ++s) {
    float v = lg[s];
    v += __shfl_down(v, 32, 64);
    v += __shfl_down(v, 16, 64);
    v += __shfl_down(v, 8, 64);
    v += __shfl_down(v, 4, 64);
    v += __shfl_down(v, 2, 64);
    v += __shfl_down(v, 1, 64);
    if (lane == 0) red[wave][s] = v;
  }
  __syncthreads();
  if (t < 9) {
    float total = red[0][t] + red[1][t] + red[2][t] + red[3][t];
    weights[b * 9 + t] = total * (1.0f / 256.0f);
  }
  __syncthreads();  // weights stores issued by all threads
  if (t == 0) {
    __threadfence();               // release: write back to coherent point
    rank = atomicAdd(counter, 1);  // device-scope
  }
  __syncthreads();
  if (rank == 7) {  // last block finalizes (uniform branch)
    __threadfence();  // acquire: invalidate stale cached lines
    if (t < 8) {
      float w[9];
      int idx[9];
#pragma unroll
      for (int s = 0; s < 9; ++s) {
        w[s] = weights[t * 9 + s];
        idx[s] = s;
      }
      for (int a = 0; a < 4; ++a) {
        int best = a;
        for (int c = a + 1; c < 9; ++c)
          if (w[idx[c]] > w[idx[best]]) best = c;
        int tmp = idx[a];
        idx[a] = idx[best];
        idx[best] = tmp;
      }
      float m = w[idx[0]];
      float e0 = expf(w[idx[0]] - m);
      float e1 = expf(w[idx[1]] - m);
      float e2 = expf(w[idx[2]] - m);
      float inv = 1.0f / (e0 + e1 + e2);
      float g[9];
#pragma unroll
      for (int s = 0; s < 9; ++s) g[s] = 0.f;
      g[idx[0]] = e0 * inv;
      g[idx[1]] = e1 * inv;
      g[idx[2]] = e2 * inv;
#pragma unroll
      for (int s = 0; s < 9; ++s) out[t * 9 + s] = g[s];
    }
    __syncthreads();
    if (t < 9) {
      int cnt = 0;
#pragma unroll
      for (int b2 = 0; b2 < 8; ++b2) cnt += (out[b2 * 9 + t] > 0.f) ? 1 : 0;
      out[72 + t] = (float)cnt;
    }
  }
}

// --------------------------- launch ----------------------------------------
extern "C" void kernel_launch(void* const* d_in, const int* in_sizes, int n_in,
                              void* d_out, int out_size, void* d_ws,
                              size_t ws_size, hipStream_t stream) {
  (void)in_sizes; (void)n_in; (void)out_size; (void)ws_size;
  const float* x      = (const float*)d_in[0];
  const float* conv_w = (const float*)d_in[1];
  const float* conv_b = (const float*)d_in[2];
  const float* gamma  = (const float*)d_in[3];
  const float* beta   = (const float*)d_in[4];
  const float* mean   = (const float*)d_in[5];
  const float* var    = (const float*)d_in[6];
  const float* fuse_w = (const float*)d_in[7];
  const float* fuse_b = (const float*)d_in[8];
  const float* w_gate = (const float*)d_in[9];

  char* ws = (char*)d_ws;
  size_t off = 0;
  auto alloc = [&](size_t bytes) {
    void* p = ws + off;
    off = (off + bytes + 255) & ~(size_t)255;
    return p;
  };
  unsigned short* Bt_all  = (unsigned short*)alloc((size_t)5 * 262144 * 2);
  unsigned short* Bt_fuse = (unsigned short*)alloc((size_t)65536 * 2);
  float* bias_all         = (float*)alloc(1280 * 4);
  unsigned short* inter0  = (unsigned short*)alloc((size_t)65536 * 256 * 2);
  unsigned short* inter1  = (unsigned short*)alloc((size_t)16384 * 256 * 2);
  float* hbuf             = (float*)alloc((size_t)256 * 256 * 4);
  float* wts              = (float*)alloc(72 * 4);
  int* counter            = (int*)alloc(4);

  prep_kernel<<<5382, 256, 0, stream>>>(conv_w, conv_b, gamma, beta, mean, var,
                                        fuse_w, Bt_all, Bt_fuse, bias_all,
                                        counter);
  layer0_kernel<<<512, 256, 0, stream>>>(x, Bt_all, bias_all, inter0);
  gemm64_kernel<<<256, 256, 0, stream>>>(
      inter0, Bt_all + 262144, bias_all + 256, inter1, 1024, 6, 3);
  megatail_kernel<<<64, 256, 0, stream>>>(inter1, Bt_all, bias_all, Bt_fuse,
                                          fuse_b, hbuf);
  fft_gate_kernel<<<8, 256, 0, stream>>>(hbuf, w_gate, wts, counter,
                                         (float*)d_out);
}

// Round 5
// 503.000 us; speedup vs baseline: 1.1404x; 1.0186x over previous
//
#include <hip/hip_runtime.h>
#include <stdint.h>

// ---------------------------------------------------------------------------
// FourierLayer: 5x [conv2x2s2 + BN(eval) + ReLU] -> fuse proj -> rFFT(32) ->
// gating (top-3 softmax) on MI355X.
//
// Pipeline (4 dispatches):
//   prep -> layer01 (fused im2col GEMM for layer0 + layer1 in LDS, HBM-bound
//           ~42us floor: 256MB X read + 8MB inter1 write)
//        -> megatail (layers 2+3+4+fuse, grid 64, barrier-free K-loops)
//        -> fft_gate (+fused finalize via last-block elect)
//
// layer01: block (n, yh) computes layer0 pixels yo in [8yh,+8) x xo [0,16)
// (128 rows x 256 ch) AND layer1 rows y1 in [4yh,+4) x x1 [0,8) (32 rows),
// which depend only on those pixels. Layer0 output never touches global:
// it is written to a 32KB LDS half-tile (k<512 from even-yo rows, k>=512
// from odd-yo rows; yo parity == fi parity in the epilogue), XOR-8 swizzled
// in layer1-A layout; layer1 runs kt 0..7 then 8..15 against the two halves.
// Layer1 B fragments load barrier-free global->VGPR (Bt1 L2-resident).
// MFMA (kt,ks) order and f2bf points identical to the old gemm64 ->
// bitwise-identical inter1.
// ---------------------------------------------------------------------------

typedef __attribute__((ext_vector_type(8))) short bf16x8;
typedef __attribute__((ext_vector_type(4))) float f32x4;

#define DEV __device__ __forceinline__
#define GLOBAL_AS __attribute__((address_space(1)))
#define LDS_AS __attribute__((address_space(3)))

DEV unsigned short f2bf(float f) {
  union { float f; uint32_t u; } v; v.f = f;
  uint32_t u = v.u;
  return (unsigned short)((u + 0x7fffu + ((u >> 16) & 1u)) >> 16);
}

DEV void async16(const void* g, void* l) {
  __builtin_amdgcn_global_load_lds((GLOBAL_AS void*)g, (LDS_AS void*)l, 16, 0, 0);
}

// --------------------------- weight prep ----------------------------------
// idx < 262144: layer0 B image [kt(16)][u(8)][c(256)][kv(8)], k=q*16+ci_l,
//               u=k>>3 (q=u>>1, ci_l=(u&1)*8+kv), ci=kt*16+ci_l.
// else l=1..4:  Bt[l][co][k=q*256+ci] (patch-Z A order). Then Bt_fuse, bias,
// and the fft_gate election counter (zeroed each iteration).
__global__ void prep_kernel(const float* __restrict__ conv_w,
                            const float* __restrict__ conv_b,
                            const float* __restrict__ gamma,
                            const float* __restrict__ beta,
                            const float* __restrict__ mean,
                            const float* __restrict__ var,
                            const float* __restrict__ fuse_w,
                            unsigned short* __restrict__ Bt_all,
                            unsigned short* __restrict__ Bt_fuse,
                            float* __restrict__ bias_all,
                            int* __restrict__ counter) {
  int idx = blockIdx.x * 256 + threadIdx.x;
  const int NB = 5 * 256 * 1024;
  if (idx < 262144) {
    int kv = idx & 7;
    int c = (idx >> 3) & 255;
    int u = (idx >> 11) & 7;
    int kt = idx >> 14;
    int q = u >> 1;
    int ci = kt * 16 + (u & 1) * 8 + kv;
    float scale = gamma[c] * rsqrtf(var[c] + 1e-5f);
    Bt_all[idx] = f2bf(conv_w[(((size_t)c * 256 + ci) << 2) + q] * scale);
  } else if (idx < NB) {
    int l = idx >> 18;  // 1..4
    int rem = idx & 262143;
    int co = rem >> 10;
    int k = rem & 1023;
    int q = k >> 8;
    int ci = k & 255;
    int lc = l * 256 + co;
    float scale = gamma[lc] * rsqrtf(var[lc] + 1e-5f);
    Bt_all[idx] = f2bf(conv_w[(((size_t)lc * 256 + ci) << 2) + q] * scale);
  } else if (idx < NB + 65536) {
    int i = idx - NB;
    Bt_fuse[i] = f2bf(fuse_w[i]);
  } else if (idx < NB + 65536 + 1280) {
    int j = idx - (NB + 65536);
    float scale = gamma[j] * rsqrtf(var[j] + 1e-5f);
    bias_all[j] = (conv_b[j] - mean[j]) * scale + beta[j];
  } else if (idx == NB + 65536 + 1280) {
    *counter = 0;
  }
}

// --------------------------- layer 0+1 fused ------------------------------
// Layer0 part: block = (n = blk>>1, yh = blk&1), rows r = (Yl>>1)*16 + xp,
// Yl in [0,16), Y_img = yh*16 + Yl. K-tile kt: ci in [kt*16,+16), all 4 q.
// As: [u(8)][rsw(128)][kv(8)] bf16, rsw = (r&0x78)|((r^(r>>3))&7).
// Bs: [u(8)][c(256)][kv(8)] bf16, staged contiguously via async16.
// Layer1 part: 32 rows r1l = y1l*8 + x1 (y1l=(rt>>5), x1=(quad*4+i)>>1),
// A = Chalf (32 rows x 512 u16, XOR-8 swizzled), two k-halves.
__global__ __launch_bounds__(256, 2) void layer01_kernel(
    const float* __restrict__ X, const unsigned short* __restrict__ Bt0,
    const unsigned short* __restrict__ Bt1, const float* __restrict__ bias0,
    const float* __restrict__ bias1, unsigned short* __restrict__ Out) {
  __shared__ __align__(16) unsigned short As[8192];     // 16 KB staging
  __shared__ __align__(16) unsigned short Bs[16384];    // 32 KB staging
  __shared__ __align__(16) unsigned short Chalf[16384]; // 32 KB C half-tile
  const int t = threadIdx.x;
  const int lane = t & 63, wave = t >> 6;
  const int n = blockIdx.x >> 1, yh = blockIdx.x & 1;
  const int m16 = lane & 15, quad = lane >> 4;
  const int rw = wave >> 1, cw = wave & 1;
  const int xq = lane & 7, ci_lo = lane >> 3;  // ci varies within wave
  const float* xn = X + (size_t)n * 262144 + (size_t)(yh * 16) * 32;

  const f32x4 zero = {0.f, 0.f, 0.f, 0.f};
  f32x4 acc[4][8];
#pragma unroll
  for (int i = 0; i < 4; ++i)
#pragma unroll
    for (int j = 0; j < 8; ++j) acc[i][j] = zero;

  for (int kt = 0; kt < 16; ++kt) {
    // B stage: 32 KB contiguous
#pragma unroll
    for (int i = 0; i < 8; ++i)
      async16(Bt0 + (size_t)kt * 16384 + (i * 256 + t) * 8,
              &Bs[(i * 256 + t) * 8]);
    // A stage: 8 float4 loads -> 32 bf16 scattered writes
#pragma unroll
    for (int j = 0; j < 8; ++j) {
      int Yl = wave * 4 + (j & 3);
      int ci_l = (j >> 2) * 8 + ci_lo;
      int ci = kt * 16 + ci_l;
      const float4 f = *(const float4*)(xn + (size_t)ci * 1024 + Yl * 32 + xq * 4);
      int qY = (Yl & 1) * 2;
      int rb = (Yl >> 1) * 16 + xq * 2;
      int cihi = ci_l >> 3, kv = ci_l & 7;
      int u0 = qY * 2 + cihi;
      int r0s = (rb & 0x78) | ((rb ^ (rb >> 3)) & 7);
      int r1 = rb + 1;
      int r1s = (r1 & 0x78) | ((r1 ^ (r1 >> 3)) & 7);
      As[u0 * 1024 + r0s * 8 + kv] = f2bf(f.x);
      As[(u0 + 2) * 1024 + r0s * 8 + kv] = f2bf(f.y);
      As[u0 * 1024 + r1s * 8 + kv] = f2bf(f.z);
      As[(u0 + 2) * 1024 + r1s * 8 + kv] = f2bf(f.w);
    }
    __syncthreads();  // drains async16 (vmcnt) + ds writes
#pragma unroll
    for (int ks = 0; ks < 2; ++ks) {
      bf16x8 af[4], bfr[8];
      int ul = ks * 4 + quad;
#pragma unroll
      for (int f = 0; f < 4; ++f) {
        int r = rw * 64 + f * 16 + m16;
        int rs = (r & 0x78) | ((r ^ (r >> 3)) & 7);
        af[f] = *(const bf16x8*)&As[ul * 1024 + rs * 8];
      }
#pragma unroll
      for (int f = 0; f < 8; ++f) {
        int c = cw * 128 + f * 16 + m16;
        bfr[f] = *(const bf16x8*)&Bs[(ul * 256 + c) * 8];
      }
#pragma unroll
      for (int fi = 0; fi < 4; ++fi)
#pragma unroll
        for (int fj = 0; fj < 8; ++fj)
          acc[fi][fj] = __builtin_amdgcn_mfma_f32_16x16x32_bf16(
              af[fi], bfr[fj], acc[fi][fj], 0, 0, 0);
    }
    __syncthreads();  // LDS free for next tile's writes
  }

  float biasv[8];
#pragma unroll
  for (int fj = 0; fj < 8; ++fj) biasv[fj] = bias0[cw * 128 + fj * 16 + m16];

  // ---- layer0 epilogue -> Chalf (layer1-A layout), one yo-parity at a time.
  // rt = rw*64 + fi*16 + quad*4 + i; yo = yh*8 + (rt>>4); yo&1 == fi&1.
  // r1l = (rw*2 + (fi>>1))*8 + quad*2 + (i>>1); k' = (i&1)*256 + col (k mod
  // 512; par=0 covers k<512 i.e. q in {0,1}, par=1 covers k>=512).
  auto write_half = [&](int par) {
#pragma unroll
    for (int fh = 0; fh < 2; ++fh) {
      const int fi = fh * 2 + par;
      const int r1base = (rw * 2 + fh) * 8 + quad * 2;
#pragma unroll
      for (int fj = 0; fj < 8; ++fj) {
        const int col = cw * 128 + fj * 16 + m16;
        f32x4 v = acc[fi][fj];
#pragma unroll
        for (int i = 0; i < 4; ++i) {
          int r1l = r1base + (i >> 1);
          int kp = ((i & 1) << 8) + col;
          Chalf[r1l * 512 + (((kp >> 3) ^ (r1l & 7)) << 3) + (kp & 7)] =
              f2bf(fmaxf(v[i] + biasv[fj], 0.f));
        }
      }
    }
  };

  // ---- layer1: 32 rows x 256 cols, K=1024 in two halves, barrier-free B.
  const unsigned short* b1B[4];
#pragma unroll
  for (int f = 0; f < 4; ++f)
    b1B[f] = Bt1 + (size_t)(wave * 64 + f * 16 + m16) * 1024;
  f32x4 acc1[2][4];
#pragma unroll
  for (int i = 0; i < 2; ++i)
#pragma unroll
    for (int j = 0; j < 4; ++j) acc1[i][j] = zero;

  auto compute_half = [&](int ktlo) {
#pragma unroll
    for (int kt = ktlo; kt < ktlo + 8; ++kt) {
#pragma unroll
      for (int ks = 0; ks < 2; ++ks) {
        const int ul = (ks << 2) + quad;
        bf16x8 af2[2], bfr[4];
#pragma unroll
        for (int f = 0; f < 2; ++f) {
          int row = f * 16 + m16;
          af2[f] = *(const bf16x8*)&Chalf[row * 512 +
                     (((kt - ktlo) * 8 + (ul ^ (row & 7))) << 3)];
        }
#pragma unroll
        for (int f = 0; f < 4; ++f)
          bfr[f] = *(const bf16x8*)(b1B[f] + kt * 64 + ul * 8);
#pragma unroll
        for (int fi2 = 0; fi2 < 2; ++fi2)
#pragma unroll
          for (int fj = 0; fj < 4; ++fj)
            acc1[fi2][fj] = __builtin_amdgcn_mfma_f32_16x16x32_bf16(
                af2[fi2], bfr[fj], acc1[fi2][fj], 0, 0, 0);
      }
    }
  };

  write_half(0);
  __syncthreads();   // Chalf (k<512) visible
  compute_half(0);
  __syncthreads();   // Chalf reads done before overwrite
  write_half(1);
  __syncthreads();   // Chalf (k>=512) visible
  compute_half(8);

  // ---- layer1 epilogue: bias+ReLU -> inter1 in patch-Z (hw_shift=6, wsh=3).
  float b1v[4];
#pragma unroll
  for (int fj = 0; fj < 4; ++fj) b1v[fj] = bias1[wave * 64 + fj * 16 + m16];
#pragma unroll
  for (int f = 0; f < 2; ++f) {
#pragma unroll
    for (int fj = 0; fj < 4; ++fj) {
      const int col = wave * 64 + fj * 16 + m16;
      f32x4 v = acc1[f][fj];
#pragma unroll
      for (int i = 0; i < 4; ++i) {
        int r1l = f * 16 + quad * 4 + i;           // 0..31
        int y = yh * 4 + (r1l >> 3), x = r1l & 7;  // 8x8 grid
        int q2 = ((y & 1) << 1) | (x & 1);
        size_t addr = ((size_t)n << 14) + ((size_t)(y >> 1) << 12) +
                      ((size_t)(x >> 1) << 10) + (q2 << 8) + col;
        Out[addr] = f2bf(fmaxf(v[i] + b1v[fj], 0.f));
      }
    }
  }
}

// --------------------------- megatail: layers 2+3+4 + fuse ------------------
// Grid 64 x 256. Block bh owns images [4bh,4bh+4): layer2 rows [64bh,+64),
// layer3 [16bh,+16), layer4 [4bh,+4), fuse [4bh,+4). Barrier-free K-loops:
// A/B fragments direct global->VGPR (offsets fold into 13-bit imm); LDS only
// for inter-layer intermediates (C2s/C3s/C4s, XOR-8 swizzled), one barrier
// per layer boundary. (kt,ks) MFMA order unchanged -> bitwise-identical.
__global__ __launch_bounds__(256, 1) void megatail_kernel(
    const unsigned short* __restrict__ A2,      // inter1 as [4096 x 1024]
    const unsigned short* __restrict__ Bt_all,  // conv weights (all layers)
    const float* __restrict__ bias_all,
    const unsigned short* __restrict__ Btf,     // fuse weights [256 x 256]
    const float* __restrict__ fbias,
    float* __restrict__ hbuf) {
  __shared__ __align__(16) unsigned short C2s[16 * 1024];  // 32 KB
  __shared__ __align__(16) unsigned short C3s[4 * 1024];   // 8 KB
  __shared__ __align__(16) unsigned short C4s[4 * 256];    // 2 KB
  const int t = threadIdx.x;
  const int lane = t & 63, wave = t >> 6;
  const int bh = blockIdx.x;
  const int m16 = lane & 15, quad = lane >> 4;
  const f32x4 zero = {0.f, 0.f, 0.f, 0.f};

  const unsigned short* Bt2 = Bt_all + 2 * 262144;
  const unsigned short* Bt3 = Bt_all + 3 * 262144;
  const unsigned short* Bt4 = Bt_all + 4 * 262144;

  // ---------------- layer 2: 64 rows, barrier-free ----------------
  {
    const unsigned short* aB[4];
    const unsigned short* bB[4];
#pragma unroll
    for (int f = 0; f < 4; ++f) {
      aB[f] = A2 + (size_t)(bh * 64 + f * 16 + m16) * 1024;
      bB[f] = Bt2 + (size_t)(wave * 64 + f * 16 + m16) * 1024;
    }
    f32x4 acc[4][4];
#pragma unroll
    for (int i = 0; i < 4; ++i)
#pragma unroll
      for (int j = 0; j < 4; ++j) acc[i][j] = zero;
#pragma unroll
    for (int kt = 0; kt < 16; ++kt) {
#pragma unroll
      for (int ks = 0; ks < 2; ++ks) {
        const int off = kt * 64 + ((ks << 2) + quad) * 8;
        bf16x8 af[4], bfr[4];
#pragma unroll
        for (int f = 0; f < 4; ++f) af[f] = *(const bf16x8*)(aB[f] + off);
#pragma unroll
        for (int f = 0; f < 4; ++f) bfr[f] = *(const bf16x8*)(bB[f] + off);
#pragma unroll
        for (int fi = 0; fi < 4; ++fi)
#pragma unroll
          for (int fj = 0; fj < 4; ++fj)
            acc[fi][fj] = __builtin_amdgcn_mfma_f32_16x16x32_bf16(
                af[fi], bfr[fj], acc[fi][fj], 0, 0, 0);
      }
    }
    // epilogue -> C2s (layer3-A layout; 4x4 image grid: n=R>>4, y,x in [0,4))
    float bv[4];
#pragma unroll
    for (int fj = 0; fj < 4; ++fj)
      bv[fj] = bias_all[512 + wave * 64 + fj * 16 + m16];
#pragma unroll
    for (int fi = 0; fi < 4; ++fi) {
#pragma unroll
      for (int fj = 0; fj < 4; ++fj) {
        int col = wave * 64 + fj * 16 + m16;
        f32x4 v = acc[fi][fj];
#pragma unroll
        for (int i = 0; i < 4; ++i) {
          int R2l = fi * 16 + quad * 4 + i;  // 0..63
          int nl = R2l >> 4;
          int y = (R2l >> 2) & 3, x = R2l & 3;
          int q2 = ((y & 1) << 1) | (x & 1);
          int P = nl * 4 + ((y >> 1) << 1) + (x >> 1);  // layer3 local row
          int k = (q2 << 8) + col;
          C2s[P * 1024 + (((k >> 3) ^ (P & 7)) << 3) + (k & 7)] =
              f2bf(fmaxf(v[i] + bv[fj], 0.f));
        }
      }
    }
  }
  __syncthreads();

  // ---------------- layer 3: 16 rows, A = C2s, barrier-free ----------------
  {
    const unsigned short* bB[4];
#pragma unroll
    for (int f = 0; f < 4; ++f)
      bB[f] = Bt3 + (size_t)(wave * 64 + f * 16 + m16) * 1024;
    f32x4 acc3[4];
#pragma unroll
    for (int j = 0; j < 4; ++j) acc3[j] = zero;
#pragma unroll
    for (int kt = 0; kt < 16; ++kt) {
#pragma unroll
      for (int ks = 0; ks < 2; ++ks) {
        const int ul = (ks << 2) + quad;
        const int off = kt * 64 + ul * 8;
        const int ra = m16;  // 0..15
        bf16x8 af =
            *(const bf16x8*)&C2s[ra * 1024 + ((kt * 8 + (ul ^ (ra & 7))) << 3)];
        bf16x8 bfr[4];
#pragma unroll
        for (int f = 0; f < 4; ++f) bfr[f] = *(const bf16x8*)(bB[f] + off);
#pragma unroll
        for (int fj = 0; fj < 4; ++fj)
          acc3[fj] = __builtin_amdgcn_mfma_f32_16x16x32_bf16(af, bfr[fj],
                                                             acc3[fj], 0, 0, 0);
      }
    }
    // epilogue -> C3s (layer4-A layout; rows quad*4+i, all 16 valid)
    float bv[4];
#pragma unroll
    for (int fj = 0; fj < 4; ++fj)
      bv[fj] = bias_all[768 + wave * 64 + fj * 16 + m16];
#pragma unroll
    for (int fj = 0; fj < 4; ++fj) {
      int col = wave * 64 + fj * 16 + m16;
      f32x4 v = acc3[fj];
#pragma unroll
      for (int i = 0; i < 4; ++i) {
        int R3l = quad * 4 + i;  // 0..15
        int nl = R3l >> 2;       // 0..3
        int k = ((R3l & 3) << 8) + col;
        C3s[nl * 1024 + (((k >> 3) ^ nl) << 3) + (k & 7)] =
            f2bf(fmaxf(v[i] + bv[fj], 0.f));
      }
    }
  }
  __syncthreads();

  // ---------------- layer 4: 4 rows, A = C3s, barrier-free -----------------
  {
    const unsigned short* bB[4];
#pragma unroll
    for (int f = 0; f < 4; ++f)
      bB[f] = Bt4 + (size_t)(wave * 64 + f * 16 + m16) * 1024;
    f32x4 acc4[4];
#pragma unroll
    for (int j = 0; j < 4; ++j) acc4[j] = zero;
#pragma unroll
    for (int kt = 0; kt < 16; ++kt) {
#pragma unroll
      for (int ks = 0; ks < 2; ++ks) {
        const int ul = (ks << 2) + quad;
        const int off = kt * 64 + ul * 8;
        const int ra = m16 & 3;  // rows 4..15 duplicate 0..3 (discarded)
        bf16x8 af =
            *(const bf16x8*)&C3s[ra * 1024 + ((kt * 8 + (ul ^ ra)) << 3)];
        bf16x8 bfr[4];
#pragma unroll
        for (int f = 0; f < 4; ++f) bfr[f] = *(const bf16x8*)(bB[f] + off);
#pragma unroll
        for (int fj = 0; fj < 4; ++fj)
          acc4[fj] = __builtin_amdgcn_mfma_f32_16x16x32_bf16(af, bfr[fj],
                                                             acc4[fj], 0, 0, 0);
      }
    }
    // epilogue -> C4s rows 0..3 (fuse-A layout, K=256)
    float bv[4];
#pragma unroll
    for (int fj = 0; fj < 4; ++fj)
      bv[fj] = bias_all[1024 + wave * 64 + fj * 16 + m16];
#pragma unroll
    for (int fj = 0; fj < 4; ++fj) {
      int col = wave * 64 + fj * 16 + m16;
      f32x4 v = acc4[fj];
#pragma unroll
      for (int i = 0; i < 4; ++i) {
        if (quad == 0) {
          int R4 = i;  // 0..3
          C4s[R4 * 256 + (((col >> 3) ^ R4) << 3) + (col & 7)] =
              f2bf(fmaxf(v[i] + bv[fj], 0.f));
        }
      }
    }
  }
  __syncthreads();

  // ---------------- fuse: 4 rows, K=256, A = C4s, barrier-free -------------
  {
    const unsigned short* bB[4];
#pragma unroll
    for (int f = 0; f < 4; ++f)
      bB[f] = Btf + (size_t)(wave * 64 + f * 16 + m16) * 256;
    f32x4 accf[4];
#pragma unroll
    for (int j = 0; j < 4; ++j) accf[j] = zero;
#pragma unroll
    for (int kt = 0; kt < 4; ++kt) {
#pragma unroll
      for (int ks = 0; ks < 2; ++ks) {
        const int ul = (ks << 2) + quad;
        const int off = kt * 64 + ul * 8;
        const int ra = m16 & 3;
        bf16x8 af = *(const bf16x8*)&C4s[ra * 256 + ((kt * 8 + (ul ^ ra)) << 3)];
        bf16x8 bfr[4];
#pragma unroll
        for (int f = 0; f < 4; ++f) bfr[f] = *(const bf16x8*)(bB[f] + off);
#pragma unroll
        for (int fj = 0; fj < 4; ++fj)
          accf[fj] = __builtin_amdgcn_mfma_f32_16x16x32_bf16(af, bfr[fj],
                                                             accf[fj], 0, 0, 0);
      }
    }
    // epilogue: f32 -> hbuf rows [4bh, 4bh+4), no ReLU
    float fb[4];
#pragma unroll
    for (int fj = 0; fj < 4; ++fj) fb[fj] = fbias[wave * 64 + fj * 16 + m16];
#pragma unroll
    for (int fj = 0; fj < 4; ++fj) {
      int col = wave * 64 + fj * 16 + m16;
      f32x4 v = accf[fj];
#pragma unroll
      for (int i = 0; i < 4; ++i) {
        if (quad == 0) {
          int R = bh * 4 + i;
          hbuf[((size_t)R << 8) + col] = v[i] + fb[fj];
        }
      }
    }
  }
}

// --------------------------- FFT + gate logits (+finalize) ------------------
// Last block (elected via device-scope atomic on a prep-zeroed counter)
// performs the top-k gates + load computation. Agent-scope __threadfence()
// provides the cross-XCD L2 writeback/invalidate.
__global__ void fft_gate_kernel(const float* __restrict__ hbuf,
                                const float* __restrict__ w_gate,
                                float* __restrict__ weights,
                                int* __restrict__ counter,
                                float* __restrict__ out) {
  __shared__ float cs[32], sn[32];
  __shared__ float wg[144];
  __shared__ float red[4][9];
  __shared__ int rank;
  const int b = blockIdx.x, t = threadIdx.x;
  if (t < 32) {
    float ang = 6.283185307179586f * (float)t / 32.0f;
    cs[t] = cosf(ang);
    sn[t] = sinf(ang);
  }
  if (t < 144) wg[t] = w_gate[t];
  __syncthreads();

  float hl[32];
#pragma unroll
  for (int tt = 0; tt < 32; ++tt) hl[tt] = hbuf[(size_t)(b * 32 + tt) * 256 + t];

  float lg[9];
#pragma unroll
  for (int s = 0; s < 9; ++s) lg[s] = 0.f;

#pragma unroll
  for (int f = 1; f <= 16; ++f) {
    float re = 0.f, im = 0.f;
#pragma unroll
    for (int tt = 0; tt < 32; ++tt) {
      int idx = (f * tt) & 31;
      re += hl[tt] * cs[idx];
      im += hl[tt] * sn[idx];
    }
    float amp = sqrtf(re * re + im * im) * 0.17677669529663687f;  // 1/sqrt(32)
#pragma unroll
    for (int s = 0; s < 9; ++s) lg[s] += amp * wg[(f - 1) * 9 + s];
  }

  const int lane = t & 63, wave = t >> 6;
#pragma unroll
  for (int s = 0; s < 9; ++s) {
    float v = lg[s];
    v += __shfl_down(v, 32, 64);
    v += __shfl_down(v, 16, 64);
    v += __shfl_down(v, 8, 64);
    v += __shfl_down(v, 4, 64);
    v += __shfl_down(v, 2, 64);
    v += __shfl_down(v, 1, 64);
    if (lane == 0) red[wave][s] = v;
  }
  __syncthreads();
  if (t < 9) {
    float total = red[0][t] + red[1][t] + red[2][t] + red[3][t];
    weights[b * 9 + t] = total * (1.0f / 256.0f);
  }
  __syncthreads();  // weights stores issued by all threads
  if (t == 0) {
    __threadfence();               // release: write back to coherent point
    rank = atomicAdd(counter, 1);  // device-scope
  }
  __syncthreads();
  if (rank == 7) {  // last block finalizes (uniform branch)
    __threadfence();  // acquire: invalidate stale cached lines
    if (t < 8) {
      float w[9];
      int idx[9];
#pragma unroll
      for (int s = 0; s < 9; ++s) {
        w[s] = weights[t * 9 + s];
        idx[s] = s;
      }
      for (int a = 0; a < 4; ++a) {
        int best = a;
        for (int c = a + 1; c < 9; ++c)
          if (w[idx[c]] > w[idx[best]]) best = c;
        int tmp = idx[a];
        idx[a] = idx[best];
        idx[best] = tmp;
      }
      float m = w[idx[0]];
      float e0 = expf(w[idx[0]] - m);
      float e1 = expf(w[idx[1]] - m);
      float e2 = expf(w[idx[2]] - m);
      float inv = 1.0f / (e0 + e1 + e2);
      float g[9];
#pragma unroll
      for (int s = 0; s < 9; ++s) g[s] = 0.f;
      g[idx[0]] = e0 * inv;
      g[idx[1]] = e1 * inv;
      g[idx[2]] = e2 * inv;
#pragma unroll
      for (int s = 0; s < 9; ++s) out[t * 9 + s] = g[s];
    }
    __syncthreads();
    if (t < 9) {
      int cnt = 0;
#pragma unroll
      for (int b2 = 0; b2 < 8; ++b2) cnt += (out[b2 * 9 + t] > 0.f) ? 1 : 0;
      out[72 + t] = (float)cnt;
    }
  }
}

// --------------------------- launch ----------------------------------------
extern "C" void kernel_launch(void* const* d_in, const int* in_sizes, int n_in,
                              void* d_out, int out_size, void* d_ws,
                              size_t ws_size, hipStream_t stream) {
  (void)in_sizes; (void)n_in; (void)out_size; (void)ws_size;
  const float* x      = (const float*)d_in[0];
  const float* conv_w = (const float*)d_in[1];
  const float* conv_b = (const float*)d_in[2];
  const float* gamma  = (const float*)d_in[3];
  const float* beta   = (const float*)d_in[4];
  const float* mean   = (const float*)d_in[5];
  const float* var    = (const float*)d_in[6];
  const float* fuse_w = (const float*)d_in[7];
  const float* fuse_b = (const float*)d_in[8];
  const float* w_gate = (const float*)d_in[9];

  char* ws = (char*)d_ws;
  size_t off = 0;
  auto alloc = [&](size_t bytes) {
    void* p = ws + off;
    off = (off + bytes + 255) & ~(size_t)255;
    return p;
  };
  unsigned short* Bt_all  = (unsigned short*)alloc((size_t)5 * 262144 * 2);
  unsigned short* Bt_fuse = (unsigned short*)alloc((size_t)65536 * 2);
  float* bias_all         = (float*)alloc(1280 * 4);
  unsigned short* inter1  = (unsigned short*)alloc((size_t)16384 * 256 * 2);
  float* hbuf             = (float*)alloc((size_t)256 * 256 * 4);
  float* wts              = (float*)alloc(72 * 4);
  int* counter            = (int*)alloc(4);

  prep_kernel<<<5382, 256, 0, stream>>>(conv_w, conv_b, gamma, beta, mean, var,
                                        fuse_w, Bt_all, Bt_fuse, bias_all,
                                        counter);
  layer01_kernel<<<512, 256, 0, stream>>>(x, Bt_all, Bt_all + 262144, bias_all,
                                          bias_all + 256, inter1);
  megatail_kernel<<<64, 256, 0, stream>>>(inter1, Bt_all, bias_all, Bt_fuse,
                                          fuse_b, hbuf);
  fft_gate_kernel<<<8, 256, 0, stream>>>(hbuf, w_gate, wts, counter,
                                         (float*)d_out);
}